// Round 1
// baseline (1138.436 us; speedup 1.0000x reference)
//
#include <hip/hip_runtime.h>
#include <hip/hip_bf16.h>
#include <stddef.h>

// GCN link predictor: 3x (GCNConv -> BN -> [sigmoid]) then edge dot-product decode.
// Strategy:
//  - Build CSR (by dst) once via counting sort; reuse for all 3 layers.
//  - Layer 1: aggregate x (F=128) then GEMM (F_in < F_out). Layers 2/3: GEMM then aggregate.
//  - Biases b1..b3 cancel exactly under training-mode BatchNorm -> skipped.
//  - All f32 (threshold is ~2% of |ref|max; f32 gives ~1e-5 rel).

#define WAVE 64

// ---------------- small helpers ----------------
template<int VEC>
__device__ __forceinline__ void vload(float (&d)[VEC], const float* __restrict__ p) {
    if constexpr (VEC == 4) { float4 v = *reinterpret_cast<const float4*>(p); d[0]=v.x; d[1]=v.y; d[2]=v.z; d[3]=v.w; }
    else if constexpr (VEC == 2) { float2 v = *reinterpret_cast<const float2*>(p); d[0]=v.x; d[1]=v.y; }
    else { d[0] = *p; }
}
template<int VEC>
__device__ __forceinline__ void vstore(float* __restrict__ p, const float (&d)[VEC]) {
    if constexpr (VEC == 4) { *reinterpret_cast<float4*>(p) = make_float4(d[0],d[1],d[2],d[3]); }
    else if constexpr (VEC == 2) { *reinterpret_cast<float2*>(p) = make_float2(d[0],d[1]); }
    else { *p = d[0]; }
}

// ---------------- CSR build ----------------
__global__ void k_hist(const int* __restrict__ dst, int* __restrict__ cnt, int E) {
    int i = blockIdx.x * blockDim.x + threadIdx.x;
    int stride = gridDim.x * blockDim.x;
    for (; i < E; i += stride) atomicAdd(&cnt[dst[i]], 1);
}

__global__ void k_dinv(const int* __restrict__ cnt, float* __restrict__ dinv, int N) {
    int i = blockIdx.x * blockDim.x + threadIdx.x;
    if (i < N) dinv[i] = rsqrtf((float)(cnt[i] + 1));   // +1 self loop
}

// scan over N ints, chunk = 1024 per block (256 thr x 4)
__global__ void k_scan1(const int* __restrict__ cnt, int* __restrict__ part, int N) {
    __shared__ int sh[256];
    int b = blockIdx.x, t = threadIdx.x;
    int base = b * 1024 + t * 4;
    int s = 0;
    #pragma unroll
    for (int j = 0; j < 4; ++j) s += (base + j < N) ? cnt[base + j] : 0;
    sh[t] = s; __syncthreads();
    for (int off = 128; off > 0; off >>= 1) {
        if (t < off) sh[t] += sh[t + off];
        __syncthreads();
    }
    if (t == 0) part[b] = sh[0];
}

__global__ void k_scan2(int* __restrict__ part, int* __restrict__ rowptr, int nch, int N, int E) {
    if (threadIdx.x == 0 && blockIdx.x == 0) {
        int acc = 0;
        for (int i = 0; i < nch; ++i) { int v = part[i]; part[i] = acc; acc += v; }
        rowptr[N] = E;
    }
}

// writes rowptr[i] (exclusive prefix) and rewrites cnt[i] := rowptr[i] (scatter cursor)
__global__ void k_scan3(int* __restrict__ cnt, int* __restrict__ rowptr, const int* __restrict__ part, int N) {
    __shared__ int sh[256];
    int b = blockIdx.x, t = threadIdx.x;
    int base = b * 1024 + t * 4;
    int v[4];
    #pragma unroll
    for (int j = 0; j < 4; ++j) v[j] = (base + j < N) ? cnt[base + j] : 0;
    int s = v[0] + v[1] + v[2] + v[3];
    sh[t] = s; __syncthreads();
    for (int off = 1; off < 256; off <<= 1) {
        int x = (t >= off) ? sh[t - off] : 0;
        __syncthreads();
        sh[t] += x;
        __syncthreads();
    }
    int p = sh[t] - s + part[b];
    #pragma unroll
    for (int j = 0; j < 4; ++j) {
        if (base + j < N) { rowptr[base + j] = p; cnt[base + j] = p; }
        p += v[j];
    }
}

__global__ void k_scatter(const int* __restrict__ src, const int* __restrict__ dst,
                          int* __restrict__ cursor, int* __restrict__ srcs, int E) {
    int i = blockIdx.x * blockDim.x + threadIdx.x;
    int stride = gridDim.x * blockDim.x;
    for (; i < E; i += stride) {
        int d = dst[i];
        int p = atomicAdd(&cursor[d], 1);
        srcs[p] = src[i];
    }
}

// ---------------- aggregation: out[i] = dinv[i]*( sum_e dinv[s]*in[s] + dinv[i]*in[i] ) ----------------
template<int F>
__global__ __launch_bounds__(256) void k_agg(const float* __restrict__ in, float* __restrict__ out,
                                             const int* __restrict__ rowptr, const int* __restrict__ srcs,
                                             const float* __restrict__ dinv, int N) {
    constexpr int VEC = F / WAVE;
    int w = blockIdx.x * 4 + (threadIdx.x >> 6);
    int lane = threadIdx.x & 63;
    if (w >= N) return;
    float di = dinv[w];
    float acc[VEC];
    {
        float v[VEC];
        vload<VEC>(v, in + (size_t)w * F + lane * VEC);
        #pragma unroll
        for (int j = 0; j < VEC; ++j) acc[j] = di * v[j];   // self loop (gets extra di at the end)
    }
    int e = rowptr[w], e1 = rowptr[w + 1];
    for (; e + 1 < e1; e += 2) {
        int s0 = srcs[e], s1 = srcs[e + 1];
        float d0 = dinv[s0], d1 = dinv[s1];
        float v0[VEC], v1[VEC];
        vload<VEC>(v0, in + (size_t)s0 * F + lane * VEC);
        vload<VEC>(v1, in + (size_t)s1 * F + lane * VEC);
        #pragma unroll
        for (int j = 0; j < VEC; ++j) acc[j] += d0 * v0[j] + d1 * v1[j];
    }
    if (e < e1) {
        int s0 = srcs[e];
        float d0 = dinv[s0];
        float v0[VEC];
        vload<VEC>(v0, in + (size_t)s0 * F + lane * VEC);
        #pragma unroll
        for (int j = 0; j < VEC; ++j) acc[j] += d0 * v0[j];
    }
    #pragma unroll
    for (int j = 0; j < VEC; ++j) acc[j] *= di;
    vstore<VEC>(out + (size_t)w * F + lane * VEC, acc);
}

// ---------------- f32 GEMM: C[M,N] = A[M,K] @ W[K,N]; BM=128 BN=64 BK=16, 256 thr, 8x4 microtile ----------------
__global__ __launch_bounds__(256) void k_gemm(const float* __restrict__ A, const float* __restrict__ W,
                                              float* __restrict__ C, int M, int K, int N) {
    __shared__ float As[16][132];   // [k][m], padded: avoids 4-way write conflicts
    __shared__ float Ws[16][64];    // [k][n]
    int m0 = blockIdx.x * 128;
    int n0 = blockIdx.y * 64;
    int t = threadIdx.x;
    int ty = t >> 4, tx = t & 15;   // 16x16 threads -> 8 rows x 4 cols each
    float acc[8][4] = {};
    for (int k0 = 0; k0 < K; k0 += 16) {
        #pragma unroll
        for (int i = 0; i < 2; ++i) {
            int id = t + i * 256;            // 512 float4s: 128 rows x 4 col-groups
            int r = id >> 2, c4 = (id & 3) * 4;
            float4 v = make_float4(0.f, 0.f, 0.f, 0.f);
            int gr = m0 + r;
            if (gr < M) v = *reinterpret_cast<const float4*>(&A[(size_t)gr * K + k0 + c4]);
            As[c4 + 0][r] = v.x; As[c4 + 1][r] = v.y; As[c4 + 2][r] = v.z; As[c4 + 3][r] = v.w;
        }
        {
            int r = t >> 4, c4 = (t & 15) * 4;
            *reinterpret_cast<float4*>(&Ws[r][c4]) =
                *reinterpret_cast<const float4*>(&W[(size_t)(k0 + r) * N + n0 + c4]);
        }
        __syncthreads();
        #pragma unroll
        for (int k = 0; k < 16; ++k) {
            float a[8], b[4];
            { float4 v = *reinterpret_cast<const float4*>(&As[k][ty * 8]);     a[0]=v.x;a[1]=v.y;a[2]=v.z;a[3]=v.w; }
            { float4 v = *reinterpret_cast<const float4*>(&As[k][ty * 8 + 4]); a[4]=v.x;a[5]=v.y;a[6]=v.z;a[7]=v.w; }
            { float4 v = *reinterpret_cast<const float4*>(&Ws[k][tx * 4]);     b[0]=v.x;b[1]=v.y;b[2]=v.z;b[3]=v.w; }
            #pragma unroll
            for (int j = 0; j < 8; ++j)
                #pragma unroll
                for (int i2 = 0; i2 < 4; ++i2) acc[j][i2] += a[j] * b[i2];
        }
        __syncthreads();
    }
    #pragma unroll
    for (int j = 0; j < 8; ++j) {
        int gr = m0 + ty * 8 + j;
        if (gr < M)
            *reinterpret_cast<float4*>(&C[(size_t)gr * N + n0 + tx * 4]) =
                make_float4(acc[j][0], acc[j][1], acc[j][2], acc[j][3]);
    }
}

// ---------------- BatchNorm ----------------
template<int F>
__global__ __launch_bounds__(256) void k_bnstats(const float* __restrict__ h, float* __restrict__ sums,
                                                 float* __restrict__ sumsq, int N) {
    constexpr int RPB = 256 / F;
    __shared__ float ssum[256], ssq[256];
    int t = threadIdx.x;
    int f = t % F;
    int r0 = blockIdx.x * RPB + t / F;
    float s = 0.f, q = 0.f;
    for (int r = r0; r < N; r += gridDim.x * RPB) {
        float v = h[(size_t)r * F + f];
        s += v; q += v * v;
    }
    ssum[t] = s; ssq[t] = q; __syncthreads();
    if (t < F) {
        float S = 0.f, Q = 0.f;
        for (int j = t; j < 256; j += F) { S += ssum[j]; Q += ssq[j]; }
        atomicAdd(&sums[t], S); atomicAdd(&sumsq[t], Q);
    }
}

__global__ void k_bnfin(const float* __restrict__ sums, const float* __restrict__ sumsq,
                        const float* __restrict__ g, const float* __restrict__ beta,
                        float* __restrict__ scale, float* __restrict__ shift, int F, float invN) {
    int f = threadIdx.x;
    if (f < F) {
        float m = sums[f] * invN;
        float var = sumsq[f] * invN - m * m;
        float sc = g[f] * rsqrtf(var + 1e-5f);
        scale[f] = sc;
        shift[f] = beta[f] - m * sc;
    }
}

template<int F, bool SIG>
__global__ __launch_bounds__(256) void k_bnapply(float* __restrict__ h, const float* __restrict__ scale,
                                                 const float* __restrict__ shift, int N) {
    size_t total = (size_t)N * F / 4;
    size_t i = (size_t)blockIdx.x * blockDim.x + threadIdx.x;
    size_t stride = (size_t)gridDim.x * blockDim.x;
    for (; i < total; i += stride) {
        float4 v = reinterpret_cast<float4*>(h)[i];
        int f = (int)((i * 4) % F);
        v.x = v.x * scale[f + 0] + shift[f + 0];
        v.y = v.y * scale[f + 1] + shift[f + 1];
        v.z = v.z * scale[f + 2] + shift[f + 2];
        v.w = v.w * scale[f + 3] + shift[f + 3];
        if (SIG) {
            v.x = 1.f / (1.f + expf(-v.x));
            v.y = 1.f / (1.f + expf(-v.y));
            v.z = 1.f / (1.f + expf(-v.z));
            v.w = 1.f / (1.f + expf(-v.w));
        }
        reinterpret_cast<float4*>(h)[i] = v;
    }
}

// ---------------- decode: logits[e] = dot64(z[a], z[b]) ----------------
__global__ __launch_bounds__(256) void k_decode(const float* __restrict__ z, const int* __restrict__ pos,
                                                const int* __restrict__ neg, int Pp, int Pn,
                                                float* __restrict__ out) {
    int gid = blockIdx.x * 16 + (threadIdx.x >> 4);
    int l = threadIdx.x & 15;
    int P = Pp + Pn;
    if (gid >= P) return;
    int a, b;
    if (gid < Pp) { a = pos[gid]; b = pos[Pp + gid]; }
    else          { int e = gid - Pp; a = neg[e]; b = neg[Pn + e]; }
    float4 va = *reinterpret_cast<const float4*>(&z[(size_t)a * 64 + l * 4]);
    float4 vb = *reinterpret_cast<const float4*>(&z[(size_t)b * 64 + l * 4]);
    float d = va.x * vb.x + va.y * vb.y + va.z * vb.z + va.w * vb.w;
    d += __shfl_xor(d, 1);
    d += __shfl_xor(d, 2);
    d += __shfl_xor(d, 4);
    d += __shfl_xor(d, 8);
    if (l == 0) out[gid] = d;
}

// ---------------- launch ----------------
extern "C" void kernel_launch(void* const* d_in, const int* in_sizes, int n_in,
                              void* d_out, int out_size, void* d_ws, size_t ws_size,
                              hipStream_t stream) {
    const float* x   = (const float*)d_in[0];
    const int*   ei  = (const int*)d_in[1];
    const int*   pe  = (const int*)d_in[2];
    const int*   ne  = (const int*)d_in[3];
    const float* W1  = (const float*)d_in[4];
    const float* g1  = (const float*)d_in[6];
    const float* be1 = (const float*)d_in[7];
    const float* W2  = (const float*)d_in[8];
    const float* g2  = (const float*)d_in[10];
    const float* be2 = (const float*)d_in[11];
    const float* W3  = (const float*)d_in[12];
    const float* g3  = (const float*)d_in[14];
    const float* be3 = (const float*)d_in[15];
    float* out = (float*)d_out;

    const int N  = in_sizes[0] / 128;
    const int E  = in_sizes[1] / 2;
    const int Pp = in_sizes[2] / 2;
    const int Pn = in_sizes[3] / 2;

    char* ws = (char*)d_ws;
    auto carve = [&](size_t bytes) -> char* {
        char* p = ws;
        ws += (bytes + 255) & ~(size_t)255;
        return p;
    };
    float* dinv   = (float*)carve((size_t)N * 4);
    int*   cnt    = (int*)carve((size_t)N * 4);          // histogram, then scatter cursor
    int*   rowptr = (int*)carve((size_t)(N + 1) * 4);
    int*   part   = (int*)carve(1024);
    int*   srcs   = (int*)carve((size_t)E * 4);
    float* sums   = (float*)carve(2048);                 // sums[256] | sumsq[256]
    float* sumsq  = sums + 256;
    float* scale  = (float*)carve(1024);
    float* shift  = (float*)carve(1024);
    float* bufA   = (float*)carve((size_t)N * 256 * 4);  // activations
    float* bufB   = (float*)carve((size_t)N * 128 * 4);  // gemm/agg ping

    const int* e_src = ei;
    const int* e_dst = ei + E;

    // ---- CSR build (once, reused by all 3 layers) ----
    hipMemsetAsync(cnt, 0, (size_t)N * 4, stream);
    k_hist<<<2048, 256, 0, stream>>>(e_dst, cnt, E);
    k_dinv<<<(N + 255) / 256, 256, 0, stream>>>(cnt, dinv, N);
    int nch = (N + 1023) / 1024;
    k_scan1<<<nch, 256, 0, stream>>>(cnt, part, N);
    k_scan2<<<1, 1, 0, stream>>>(part, rowptr, nch, N, E);
    k_scan3<<<nch, 256, 0, stream>>>(cnt, rowptr, part, N);
    k_scatter<<<2048, 256, 0, stream>>>(e_src, e_dst, cnt, srcs, E);

    int aggBlocks = (N + 3) / 4;
    // ---- Layer 1: agg(x) [N,128] -> GEMM -> BN+sigmoid ----
    k_agg<128><<<aggBlocks, 256, 0, stream>>>(x, bufB, rowptr, srcs, dinv, N);
    {
        dim3 g((N + 127) / 128, 4);
        k_gemm<<<g, 256, 0, stream>>>(bufB, W1, bufA, N, 128, 256);
    }
    hipMemsetAsync(sums, 0, 2048, stream);
    k_bnstats<256><<<512, 256, 0, stream>>>(bufA, sums, sumsq, N);
    k_bnfin<<<1, 256, 0, stream>>>(sums, sumsq, g1, be1, scale, shift, 256, 1.0f / N);
    k_bnapply<256, true><<<4096, 256, 0, stream>>>(bufA, scale, shift, N);

    // ---- Layer 2: GEMM [N,128] -> agg -> BN+sigmoid ----
    {
        dim3 g((N + 127) / 128, 2);
        k_gemm<<<g, 256, 0, stream>>>(bufA, W2, bufB, N, 256, 128);
    }
    k_agg<128><<<aggBlocks, 256, 0, stream>>>(bufB, bufA, rowptr, srcs, dinv, N);
    hipMemsetAsync(sums, 0, 2048, stream);
    k_bnstats<128><<<512, 256, 0, stream>>>(bufA, sums, sumsq, N);
    k_bnfin<<<1, 256, 0, stream>>>(sums, sumsq, g2, be2, scale, shift, 128, 1.0f / N);
    k_bnapply<128, true><<<4096, 256, 0, stream>>>(bufA, scale, shift, N);

    // ---- Layer 3: GEMM [N,64] -> agg -> BN (no sigmoid) ----
    {
        dim3 g((N + 127) / 128, 1);
        k_gemm<<<g, 256, 0, stream>>>(bufA, W3, bufB, N, 128, 64);
    }
    k_agg<64><<<aggBlocks, 256, 0, stream>>>(bufB, bufA, rowptr, srcs, dinv, N);
    hipMemsetAsync(sums, 0, 2048, stream);
    k_bnstats<64><<<512, 256, 0, stream>>>(bufA, sums, sumsq, N);
    k_bnfin<<<1, 256, 0, stream>>>(sums, sumsq, g3, be3, scale, shift, 64, 1.0f / N);
    k_bnapply<64, false><<<4096, 256, 0, stream>>>(bufA, scale, shift, N);

    // ---- decode ----
    k_decode<<<(Pp + Pn + 15) / 16, 256, 0, stream>>>(bufA, pe, ne, Pp, Pn, out);
}

// Round 2
// 883.695 us; speedup vs baseline: 1.2883x; 1.2883x over previous
//
#include <hip/hip_runtime.h>
#include <hip/hip_bf16.h>
#include <stddef.h>

// GCN link predictor: 3x (GCNConv -> BN -> [sigmoid]) then edge dot decode.
//  - CSR (by dst) built once via counting sort; reused for all 3 layers.
//  - bf16 activations everywhere (threshold = 2% of |ref|max; bf16 ~0.2% rel).
//  - GEMMs: bf16 MFMA 16x16x32, no LDS (A + W^T fragments direct from global).
//  - Biases cancel under training-mode BN -> skipped.

#define WAVE 64

typedef __attribute__((ext_vector_type(8))) short short8;
typedef __attribute__((ext_vector_type(4))) float f32x4;

__device__ __forceinline__ float bl(uint g) { return __uint_as_float(g << 16); }
__device__ __forceinline__ float bh(uint g) { return __uint_as_float(g & 0xffff0000u); }
__device__ __forceinline__ ushort f2b(float f) {           // round-to-nearest-even
    uint u = __float_as_uint(f);
    return (ushort)((u + 0x7fffu + ((u >> 16) & 1u)) >> 16);
}
__device__ __forceinline__ uint pack2(float lo, float hi) {
    return (uint)f2b(lo) | ((uint)f2b(hi) << 16);
}

// ---------------- CSR build ----------------
__global__ void k_hist(const int* __restrict__ dst, int* __restrict__ cnt, int E) {
    int i = blockIdx.x * blockDim.x + threadIdx.x;
    int stride = gridDim.x * blockDim.x;
    for (; i < E; i += stride) atomicAdd(&cnt[dst[i]], 1);
}

__global__ void k_dinv(const int* __restrict__ cnt, float* __restrict__ dinv, int N) {
    int i = blockIdx.x * blockDim.x + threadIdx.x;
    if (i < N) dinv[i] = rsqrtf((float)(cnt[i] + 1));   // +1 self loop
}

__global__ void k_scan1(const int* __restrict__ cnt, int* __restrict__ part, int N) {
    __shared__ int sh[256];
    int b = blockIdx.x, t = threadIdx.x;
    int base = b * 1024 + t * 4;
    int s = 0;
    #pragma unroll
    for (int j = 0; j < 4; ++j) s += (base + j < N) ? cnt[base + j] : 0;
    sh[t] = s; __syncthreads();
    for (int off = 128; off > 0; off >>= 1) {
        if (t < off) sh[t] += sh[t + off];
        __syncthreads();
    }
    if (t == 0) part[b] = sh[0];
}

__global__ void k_scan2(int* __restrict__ part, int* __restrict__ rowptr, int nch, int N, int E) {
    if (threadIdx.x == 0 && blockIdx.x == 0) {
        int acc = 0;
        for (int i = 0; i < nch; ++i) { int v = part[i]; part[i] = acc; acc += v; }
        rowptr[N] = E;
    }
}

__global__ void k_scan3(int* __restrict__ cnt, int* __restrict__ rowptr, const int* __restrict__ part, int N) {
    __shared__ int sh[256];
    int b = blockIdx.x, t = threadIdx.x;
    int base = b * 1024 + t * 4;
    int v[4];
    #pragma unroll
    for (int j = 0; j < 4; ++j) v[j] = (base + j < N) ? cnt[base + j] : 0;
    int s = v[0] + v[1] + v[2] + v[3];
    sh[t] = s; __syncthreads();
    for (int off = 1; off < 256; off <<= 1) {
        int x = (t >= off) ? sh[t - off] : 0;
        __syncthreads();
        sh[t] += x;
        __syncthreads();
    }
    int p = sh[t] - s + part[b];
    #pragma unroll
    for (int j = 0; j < 4; ++j) {
        if (base + j < N) { rowptr[base + j] = p; cnt[base + j] = p; }
        p += v[j];
    }
}

__global__ void k_scatter(const int* __restrict__ src, const int* __restrict__ dst,
                          int* __restrict__ cursor, int* __restrict__ srcs, int E) {
    int i = blockIdx.x * blockDim.x + threadIdx.x;
    int stride = gridDim.x * blockDim.x;
    for (; i < E; i += stride) {
        int d = dst[i];
        int p = atomicAdd(&cursor[d], 1);
        srcs[p] = src[i];
    }
}

// ---------------- conversions ----------------
__global__ void k_convx(const float* __restrict__ in, ushort* __restrict__ out, size_t n4) {
    size_t i = (size_t)blockIdx.x * blockDim.x + threadIdx.x;
    if (i >= n4) return;
    float4 v = reinterpret_cast<const float4*>(in)[i];
    uint2 o;
    o.x = pack2(v.x, v.y);
    o.y = pack2(v.z, v.w);
    reinterpret_cast<uint2*>(out)[i] = o;
}

// Wt[n*K + k] = bf16(W[k*N + n])
__global__ void k_convWT(const float* __restrict__ W, ushort* __restrict__ Wt, int K, int N) {
    int i = blockIdx.x * blockDim.x + threadIdx.x;
    if (i >= K * N) return;
    int k = i / N, n = i % N;
    Wt[(size_t)n * K + k] = f2b(W[i]);
}

// ---------------- aggregation (bf16 in / bf16 out, f32 accum) ----------------
// out[i] = dinv[i]*( sum_e dinv[s]*in[s] + dinv[i]*in[i] )
template<int F>
__global__ __launch_bounds__(256) void k_agg(const ushort* __restrict__ in, ushort* __restrict__ out,
                                             const int* __restrict__ rowptr, const int* __restrict__ srcs,
                                             const float* __restrict__ dinv, int N) {
    constexpr int LPN = F / 2;                       // lanes per node (1 uint = 2 bf16 per lane)
    int gt = blockIdx.x * 256 + threadIdx.x;
    int node = gt / LPN;
    int sl = gt % LPN;
    if (node >= N) return;
    const uint* inu = reinterpret_cast<const uint*>(in);
    float di = dinv[node];
    float a0, a1;
    {
        uint g = inu[(size_t)node * LPN + sl];
        a0 = di * bl(g); a1 = di * bh(g);            // self loop (x di again at end)
    }
    int e = rowptr[node], e1 = rowptr[node + 1];
    for (; e + 1 < e1; e += 2) {
        int s0 = srcs[e], s1 = srcs[e + 1];
        float d0 = dinv[s0], d1 = dinv[s1];
        uint g0 = inu[(size_t)s0 * LPN + sl];
        uint g1 = inu[(size_t)s1 * LPN + sl];
        a0 += d0 * bl(g0) + d1 * bl(g1);
        a1 += d0 * bh(g0) + d1 * bh(g1);
    }
    if (e < e1) {
        int s0 = srcs[e];
        float d0 = dinv[s0];
        uint g0 = inu[(size_t)s0 * LPN + sl];
        a0 += d0 * bl(g0);
        a1 += d0 * bh(g0);
    }
    reinterpret_cast<uint*>(out)[(size_t)node * LPN + sl] = pack2(a0 * di, a1 * di);
}

// ---------------- MFMA bf16 GEMM (no LDS): C[M,Nout] = A[M,K] @ Wt[Nout,K]^T ----------------
// Block 256 thr = 4 waves (2x2). BM=128, BN=64; wave tile 64x32 = 4x2 frags of 16x16, K-step 32.
template<int K>
__global__ __launch_bounds__(256) void k_mfma(const ushort* __restrict__ A, const ushort* __restrict__ Wt,
                                              ushort* __restrict__ C, int M, int Nout) {
    int m0 = blockIdx.x * 128;
    int n0 = blockIdx.y * 64;
    int w = threadIdx.x >> 6, lane = threadIdx.x & 63;
    int wr = w >> 1, wc = w & 1;
    int rf = lane & 15;          // row within A-frag / col within B-frag
    int kg = lane >> 4;          // k-group -> k offset kg*8

    const ushort* ap[4];
    #pragma unroll
    for (int mf = 0; mf < 4; ++mf) {
        int row = m0 + wr * 64 + mf * 16 + rf;
        if (row >= M) row = M - 1;                   // clamp; store is guarded
        ap[mf] = A + (size_t)row * K + kg * 8;
    }
    const ushort* bp[2];
    #pragma unroll
    for (int nf = 0; nf < 2; ++nf)
        bp[nf] = Wt + (size_t)(n0 + wc * 32 + nf * 16 + rf) * K + kg * 8;

    f32x4 acc[4][2];
    #pragma unroll
    for (int mf = 0; mf < 4; ++mf)
        #pragma unroll
        for (int nf = 0; nf < 2; ++nf)
            acc[mf][nf] = (f32x4){0.f, 0.f, 0.f, 0.f};

    #pragma unroll 2
    for (int kk = 0; kk < K / 32; ++kk) {
        short8 a[4], b[2];
        #pragma unroll
        for (int mf = 0; mf < 4; ++mf)
            a[mf] = *reinterpret_cast<const short8*>(ap[mf] + kk * 32);
        #pragma unroll
        for (int nf = 0; nf < 2; ++nf)
            b[nf] = *reinterpret_cast<const short8*>(bp[nf] + kk * 32);
        #pragma unroll
        for (int mf = 0; mf < 4; ++mf)
            #pragma unroll
            for (int nf = 0; nf < 2; ++nf)
                acc[mf][nf] = __builtin_amdgcn_mfma_f32_16x16x32_bf16(a[mf], b[nf], acc[mf][nf], 0, 0, 0);
    }

    #pragma unroll
    for (int mf = 0; mf < 4; ++mf)
        #pragma unroll
        for (int nf = 0; nf < 2; ++nf) {
            int col = n0 + wc * 32 + nf * 16 + rf;
            #pragma unroll
            for (int j = 0; j < 4; ++j) {
                int row = m0 + wr * 64 + mf * 16 + kg * 4 + j;
                if (row < M) C[(size_t)row * Nout + col] = f2b(acc[mf][nf][j]);
            }
        }
}

// ---------------- BatchNorm ----------------
template<int F>
__global__ __launch_bounds__(256) void k_bnstats(const ushort* __restrict__ h, float* __restrict__ sums,
                                                 float* __restrict__ sumsq, int N) {
    constexpr int RPB = 256 / F;
    __shared__ float ssum[256], ssq[256];
    int t = threadIdx.x;
    int f = t % F;
    int r0 = blockIdx.x * RPB + t / F;
    float s = 0.f, q = 0.f;
    for (int r = r0; r < N; r += gridDim.x * RPB) {
        float v = __uint_as_float(((uint)h[(size_t)r * F + f]) << 16);
        s += v; q += v * v;
    }
    ssum[t] = s; ssq[t] = q; __syncthreads();
    if (t < F) {
        float S = 0.f, Q = 0.f;
        for (int j = t; j < 256; j += F) { S += ssum[j]; Q += ssq[j]; }
        atomicAdd(&sums[t], S); atomicAdd(&sumsq[t], Q);
    }
}

__global__ void k_bnfin(const float* __restrict__ sums, const float* __restrict__ sumsq,
                        const float* __restrict__ g, const float* __restrict__ beta,
                        float* __restrict__ scale, float* __restrict__ shift, int F, float invN) {
    int f = threadIdx.x;
    if (f < F) {
        float m = sums[f] * invN;
        float var = sumsq[f] * invN - m * m;
        float sc = g[f] * rsqrtf(var + 1e-5f);
        scale[f] = sc;
        shift[f] = beta[f] - m * sc;
    }
}

// reads bf16, applies scale/shift (+sigmoid), writes bf16 or f32
template<int F, bool SIG, bool OUTF32>
__global__ __launch_bounds__(256) void k_bnapply(const ushort* __restrict__ h, void* __restrict__ outp,
                                                 const float* __restrict__ scale,
                                                 const float* __restrict__ shift, int N) {
    size_t total = (size_t)N * F / 8;
    size_t i = (size_t)blockIdx.x * blockDim.x + threadIdx.x;
    size_t stride = (size_t)gridDim.x * blockDim.x;
    for (; i < total; i += stride) {
        uint4 v = reinterpret_cast<const uint4*>(h)[i];
        int f = (int)((i * 8) % F);
        float x[8];
        x[0] = bl(v.x); x[1] = bh(v.x); x[2] = bl(v.y); x[3] = bh(v.y);
        x[4] = bl(v.z); x[5] = bh(v.z); x[6] = bl(v.w); x[7] = bh(v.w);
        #pragma unroll
        for (int j = 0; j < 8; ++j) {
            x[j] = x[j] * scale[f + j] + shift[f + j];
            if (SIG) x[j] = 1.f / (1.f + __expf(-x[j]));
        }
        if (OUTF32) {
            float4* o = reinterpret_cast<float4*>(outp);
            o[2 * i + 0] = make_float4(x[0], x[1], x[2], x[3]);
            o[2 * i + 1] = make_float4(x[4], x[5], x[6], x[7]);
        } else {
            uint4 o;
            o.x = pack2(x[0], x[1]); o.y = pack2(x[2], x[3]);
            o.z = pack2(x[4], x[5]); o.w = pack2(x[6], x[7]);
            reinterpret_cast<uint4*>(outp)[i] = o;
        }
    }
}

// ---------------- decode: logits[e] = dot64(z[a], z[b]) ----------------
__global__ __launch_bounds__(256) void k_decode(const float* __restrict__ z, const int* __restrict__ pos,
                                                const int* __restrict__ neg, int Pp, int Pn,
                                                float* __restrict__ out) {
    int gid = blockIdx.x * 16 + (threadIdx.x >> 4);
    int l = threadIdx.x & 15;
    int P = Pp + Pn;
    if (gid >= P) return;
    int a, b;
    if (gid < Pp) { a = pos[gid]; b = pos[Pp + gid]; }
    else          { int e = gid - Pp; a = neg[e]; b = neg[Pn + e]; }
    float4 va = *reinterpret_cast<const float4*>(&z[(size_t)a * 64 + l * 4]);
    float4 vb = *reinterpret_cast<const float4*>(&z[(size_t)b * 64 + l * 4]);
    float d = va.x * vb.x + va.y * vb.y + va.z * vb.z + va.w * vb.w;
    d += __shfl_xor(d, 1);
    d += __shfl_xor(d, 2);
    d += __shfl_xor(d, 4);
    d += __shfl_xor(d, 8);
    if (l == 0) out[gid] = d;
}

// ---------------- launch ----------------
extern "C" void kernel_launch(void* const* d_in, const int* in_sizes, int n_in,
                              void* d_out, int out_size, void* d_ws, size_t ws_size,
                              hipStream_t stream) {
    const float* x   = (const float*)d_in[0];
    const int*   ei  = (const int*)d_in[1];
    const int*   pe  = (const int*)d_in[2];
    const int*   ne  = (const int*)d_in[3];
    const float* W1  = (const float*)d_in[4];
    const float* g1  = (const float*)d_in[6];
    const float* be1 = (const float*)d_in[7];
    const float* W2  = (const float*)d_in[8];
    const float* g2  = (const float*)d_in[10];
    const float* be2 = (const float*)d_in[11];
    const float* W3  = (const float*)d_in[12];
    const float* g3  = (const float*)d_in[14];
    const float* be3 = (const float*)d_in[15];
    float* out = (float*)d_out;

    const int N  = in_sizes[0] / 128;
    const int E  = in_sizes[1] / 2;
    const int Pp = in_sizes[2] / 2;
    const int Pn = in_sizes[3] / 2;

    char* ws = (char*)d_ws;
    auto carve = [&](size_t bytes) -> char* {
        char* p = ws;
        ws += (bytes + 255) & ~(size_t)255;
        return p;
    };
    float*  dinv   = (float*)carve((size_t)N * 4);
    int*    cnt    = (int*)carve((size_t)N * 4);
    int*    rowptr = (int*)carve((size_t)(N + 1) * 4);
    int*    part   = (int*)carve(1024);
    int*    srcs   = (int*)carve((size_t)E * 4);
    float*  sums   = (float*)carve(2048);
    float*  sumsq  = sums + 256;
    float*  scale  = (float*)carve(1024);
    float*  shift  = (float*)carve(1024);
    ushort* Wt1    = (ushort*)carve(128 * 256 * 2);
    ushort* Wt2    = (ushort*)carve(256 * 128 * 2);
    ushort* Wt3    = (ushort*)carve(128 * 64 * 2);
    ushort* bufA   = (ushort*)carve((size_t)N * 128 * 2);   // xb / gemm2-out / gemm3-out
    ushort* bufB   = (ushort*)carve((size_t)N * 128 * 2);   // agg outs
    ushort* bufC   = (ushort*)carve((size_t)N * 256 * 2);   // h1 (N x 256)
    float*  z      = (float*)carve((size_t)N * 64 * 4);

    const int* e_src = ei;
    const int* e_dst = ei + E;

    // ---- CSR build (once) ----
    hipMemsetAsync(cnt, 0, (size_t)N * 4, stream);
    k_hist<<<2048, 256, 0, stream>>>(e_dst, cnt, E);
    k_dinv<<<(N + 255) / 256, 256, 0, stream>>>(cnt, dinv, N);
    int nch = (N + 1023) / 1024;
    k_scan1<<<nch, 256, 0, stream>>>(cnt, part, N);
    k_scan2<<<1, 1, 0, stream>>>(part, rowptr, nch, N, E);
    k_scan3<<<nch, 256, 0, stream>>>(cnt, rowptr, part, N);
    k_scatter<<<2048, 256, 0, stream>>>(e_src, e_dst, cnt, srcs, E);

    // ---- conversions ----
    {
        size_t n4 = (size_t)N * 128 / 4;
        k_convx<<<(int)((n4 + 255) / 256), 256, 0, stream>>>(x, bufA, n4);
        k_convWT<<<(128 * 256 + 255) / 256, 256, 0, stream>>>(W1, Wt1, 128, 256);
        k_convWT<<<(256 * 128 + 255) / 256, 256, 0, stream>>>(W2, Wt2, 256, 128);
        k_convWT<<<(128 * 64 + 255) / 256, 256, 0, stream>>>(W3, Wt3, 128, 64);
    }

    const int mblk = (N + 127) / 128;

    // ---- Layer 1: agg(xb)[N,128] -> MFMA GEMM -> BN+sigmoid (in bufC) ----
    k_agg<128><<<(N * 64 + 255) / 256, 256, 0, stream>>>(bufA, bufB, rowptr, srcs, dinv, N);
    { dim3 g(mblk, 4); k_mfma<128><<<g, 256, 0, stream>>>(bufB, Wt1, bufC, N, 256); }
    hipMemsetAsync(sums, 0, 2048, stream);
    k_bnstats<256><<<512, 256, 0, stream>>>(bufC, sums, sumsq, N);
    k_bnfin<<<1, 256, 0, stream>>>(sums, sumsq, g1, be1, scale, shift, 256, 1.0f / N);
    k_bnapply<256, true, false><<<4096, 256, 0, stream>>>(bufC, bufC, scale, shift, N);

    // ---- Layer 2: GEMM [N,128] -> agg -> BN+sigmoid (in bufB) ----
    { dim3 g(mblk, 2); k_mfma<256><<<g, 256, 0, stream>>>(bufC, Wt2, bufA, N, 128); }
    k_agg<128><<<(N * 64 + 255) / 256, 256, 0, stream>>>(bufA, bufB, rowptr, srcs, dinv, N);
    hipMemsetAsync(sums, 0, 2048, stream);
    k_bnstats<128><<<512, 256, 0, stream>>>(bufB, sums, sumsq, N);
    k_bnfin<<<1, 256, 0, stream>>>(sums, sumsq, g2, be2, scale, shift, 128, 1.0f / N);
    k_bnapply<128, true, false><<<4096, 256, 0, stream>>>(bufB, bufB, scale, shift, N);

    // ---- Layer 3: GEMM [N,64] -> agg -> BN (no sigmoid), f32 z ----
    { dim3 g(mblk, 1); k_mfma<128><<<g, 256, 0, stream>>>(bufB, Wt3, bufA, N, 64); }
    k_agg<64><<<(N * 32 + 255) / 256, 256, 0, stream>>>(bufA, bufB, rowptr, srcs, dinv, N);
    hipMemsetAsync(sums, 0, 2048, stream);
    k_bnstats<64><<<512, 256, 0, stream>>>(bufB, sums, sumsq, N);
    k_bnfin<<<1, 256, 0, stream>>>(sums, sumsq, g3, be3, scale, shift, 64, 1.0f / N);
    k_bnapply<64, false, true><<<4096, 256, 0, stream>>>(bufB, z, scale, shift, N);

    // ---- decode ----
    k_decode<<<(Pp + Pn + 15) / 16, 256, 0, stream>>>(z, pe, ne, Pp, Pn, out);
}

// Round 3
// 806.141 us; speedup vs baseline: 1.4122x; 1.0962x over previous
//
#include <hip/hip_runtime.h>
#include <hip/hip_bf16.h>
#include <stddef.h>

// GCN link predictor: 3x (GCNConv -> BN -> [sigmoid]) then edge dot decode.
//  - CSR by dst built once per call via 2-level binned counting sort (write-coalesced).
//  - bf16 activations; MFMA 16x16x32 GEMMs (no LDS, fragments direct from global).
//  - BN stats fused into producer epilogues (GEMM1 / agg2 / agg3).
//  - BN apply+sigmoid fused into consumer loads (GEMM2 / GEMM3 / decode).
//  - Biases cancel under training-mode BN -> skipped.

#define WAVE 64
#define BSHIFT 9                    // 512 nodes per coarse bucket (N <= 131072)
#define SCHUNK 4096                 // edges per bscatter block

typedef __attribute__((ext_vector_type(8))) short short8;
typedef __attribute__((ext_vector_type(4))) float f32x4;

__device__ __forceinline__ float bl(uint g) { return __uint_as_float(g << 16); }
__device__ __forceinline__ float bh(uint g) { return __uint_as_float(g & 0xffff0000u); }
__device__ __forceinline__ ushort f2b(float f) {           // round-to-nearest-even
    uint u = __float_as_uint(f);
    return (ushort)((u + 0x7fffu + ((u >> 16) & 1u)) >> 16);
}
__device__ __forceinline__ uint pack2(float lo, float hi) {
    return (uint)f2b(lo) | ((uint)f2b(hi) << 16);
}

// ================= binned counting sort (CSR build) =================
__global__ __launch_bounds__(256) void k_bhist(const int* __restrict__ dst, int* __restrict__ gh, int E) {
    __shared__ int lh[256];
    lh[threadIdx.x] = 0; __syncthreads();
    int i = blockIdx.x * 256 + threadIdx.x, stride = gridDim.x * 256;
    for (; i < E; i += stride) atomicAdd(&lh[dst[i] >> BSHIFT], 1);
    __syncthreads();
    int v = lh[threadIdx.x];
    if (v) atomicAdd(&gh[threadIdx.x], v);
}

__global__ void k_bscan(const int* __restrict__ gh, int* __restrict__ boff, int* __restrict__ bcur) {
    __shared__ int ls[256];
    int t = threadIdx.x;
    int v = gh[t];
    ls[t] = v; __syncthreads();
    for (int off = 1; off < 256; off <<= 1) {
        int x = (t >= off) ? ls[t - off] : 0;
        __syncthreads();
        ls[t] += x;
        __syncthreads();
    }
    int excl = ls[t] - v;
    boff[t] = excl; bcur[t] = excl;
    if (t == 255) boff[256] = ls[255];
}

__global__ __launch_bounds__(256) void k_bscatter(const int* __restrict__ src, const int* __restrict__ dst,
                                                  int* __restrict__ gcur, int2* __restrict__ pairs, int E) {
    __shared__ int lh[256];
    int t = threadIdx.x;
    int base = blockIdx.x * SCHUNK;
    lh[t] = 0; __syncthreads();
    int rs[16], rd[16];
    #pragma unroll
    for (int i = 0; i < 16; ++i) {
        int idx = base + i * 256 + t;
        if (idx < E) { rs[i] = src[idx]; rd[i] = dst[idx]; atomicAdd(&lh[rd[i] >> BSHIFT], 1); }
        else rd[i] = -1;
    }
    __syncthreads();
    int cnt_b = lh[t];
    int b0 = cnt_b ? atomicAdd(&gcur[t], cnt_b) : 0;
    lh[t] = b0;
    __syncthreads();
    #pragma unroll
    for (int i = 0; i < 16; ++i) {
        if (rd[i] >= 0) {
            int p = atomicAdd(&lh[rd[i] >> BSHIFT], 1);
            pairs[p] = make_int2(rs[i], rd[i]);
        }
    }
}

// per-bucket: fine counting sort; also emits rowptr + dinv
__global__ __launch_bounds__(256) void k_bfine(const int2* __restrict__ pairs, const int* __restrict__ boff,
                                               int* __restrict__ rowptr, int* __restrict__ srcs,
                                               float* __restrict__ dinv, int N, int E) {
    __shared__ int lcnt[512];
    __shared__ int ls[256];
    int b = blockIdx.x, t = threadIdx.x;
    int d0 = b << BSHIFT;
    int e0 = boff[b], e1 = boff[b + 1];
    lcnt[t] = 0; lcnt[t + 256] = 0;
    __syncthreads();
    for (int e = e0 + t; e < e1; e += 256)
        atomicAdd(&lcnt[pairs[e].y - d0], 1);
    __syncthreads();
    int c0 = lcnt[2 * t], c1 = lcnt[2 * t + 1];
    ls[t] = c0 + c1;
    __syncthreads();
    for (int off = 1; off < 256; off <<= 1) {
        int x = (t >= off) ? ls[t - off] : 0;
        __syncthreads();
        ls[t] += x;
        __syncthreads();
    }
    int excl = ls[t] - (c0 + c1);
    int s0 = excl, s1 = excl + c0;
    int d = d0 + 2 * t;
    if (d < N)     { rowptr[d] = e0 + s0;     dinv[d] = rsqrtf((float)(c0 + 1)); }
    if (d + 1 < N) { rowptr[d + 1] = e0 + s1; dinv[d + 1] = rsqrtf((float)(c1 + 1)); }
    if (b == 0 && t == 0) rowptr[N] = E;
    lcnt[2 * t] = s0; lcnt[2 * t + 1] = s1;
    __syncthreads();
    for (int e = e0 + t; e < e1; e += 256) {
        int2 p = pairs[e];
        int pos = atomicAdd(&lcnt[p.y - d0], 1);
        srcs[e0 + pos] = p.x;
    }
}

// ================= conversions =================
__global__ void k_convx(const float* __restrict__ in, ushort* __restrict__ out, size_t n4) {
    size_t i = (size_t)blockIdx.x * blockDim.x + threadIdx.x;
    if (i >= n4) return;
    float4 v = reinterpret_cast<const float4*>(in)[i];
    uint2 o;
    o.x = pack2(v.x, v.y);
    o.y = pack2(v.z, v.w);
    reinterpret_cast<uint2*>(out)[i] = o;
}

// Wt[n*K + k] = bf16(W[k*N + n])
__global__ void k_convWT(const float* __restrict__ W, ushort* __restrict__ Wt, int K, int N) {
    int i = blockIdx.x * blockDim.x + threadIdx.x;
    if (i >= K * N) return;
    int k = i / N, n = i % N;
    Wt[(size_t)n * K + k] = f2b(W[i]);
}

// ================= aggregation (grid-stride, optional fused BN stats) =================
// out[i] = dinv[i]*( sum_e dinv[s]*in[s] + dinv[i]*in[i] )
template<int F, bool STATS>
__global__ __launch_bounds__(256) void k_agg(const ushort* __restrict__ in, ushort* __restrict__ out,
                                             const int* __restrict__ rowptr, const int* __restrict__ srcs,
                                             const float* __restrict__ dinv, int N,
                                             float* __restrict__ gsum, float* __restrict__ gsq) {
    constexpr int LPN = F / 2;           // lanes per node (uint = 2 bf16)
    constexpr int NPW = 64 / LPN;        // nodes per wave
    int wv = threadIdx.x >> 6, lane = threadIdx.x & 63;
    int sub = lane / LPN;
    int sl = lane % LPN;
    int gw = blockIdx.x * 4 + wv;
    int totalW = gridDim.x * 4;
    const uint* inu = reinterpret_cast<const uint*>(in);
    uint* outu = reinterpret_cast<uint*>(out);
    float st_s0 = 0.f, st_s1 = 0.f, st_q0 = 0.f, st_q1 = 0.f;

    for (int nb = gw * NPW; nb < N; nb += totalW * NPW) {
        int node = nb + sub;
        bool act = node < N;
        float di = act ? dinv[node] : 0.f;
        float a0 = 0.f, a1 = 0.f;
        int e = 0, e1 = 0;
        if (act) {
            uint g = inu[(size_t)node * LPN + sl];
            a0 = di * bl(g); a1 = di * bh(g);
            e = rowptr[node]; e1 = rowptr[node + 1];
        }
        for (; e + 1 < e1; e += 2) {
            int s0i = srcs[e], s1i = srcs[e + 1];
            float d0 = dinv[s0i], d1 = dinv[s1i];
            uint g0 = inu[(size_t)s0i * LPN + sl];
            uint g1 = inu[(size_t)s1i * LPN + sl];
            a0 += d0 * bl(g0) + d1 * bl(g1);
            a1 += d0 * bh(g0) + d1 * bh(g1);
        }
        if (e < e1) {
            int s0i = srcs[e];
            float d0 = dinv[s0i];
            uint g0 = inu[(size_t)s0i * LPN + sl];
            a0 += d0 * bl(g0);
            a1 += d0 * bh(g0);
        }
        if (act) {
            float o0 = a0 * di, o1 = a1 * di;
            outu[(size_t)node * LPN + sl] = pack2(o0, o1);
            if (STATS) { st_s0 += o0; st_s1 += o1; st_q0 += o0 * o0; st_q1 += o1 * o1; }
        }
    }

    if constexpr (STATS) {
        __shared__ float ss0[256], ss1[256], sq0[256], sq1[256];
        int t = threadIdx.x;
        ss0[t] = st_s0; ss1[t] = st_s1; sq0[t] = st_q0; sq1[t] = st_q1;
        __syncthreads();
        if (t < LPN) {
            float S0 = 0.f, S1 = 0.f, Q0 = 0.f, Q1 = 0.f;
            for (int k = t; k < 256; k += LPN) { S0 += ss0[k]; S1 += ss1[k]; Q0 += sq0[k]; Q1 += sq1[k]; }
            atomicAdd(&gsum[2 * t], S0); atomicAdd(&gsum[2 * t + 1], S1);
            atomicAdd(&gsq[2 * t], Q0);  atomicAdd(&gsq[2 * t + 1], Q1);
        }
    }
}

// ================= MFMA bf16 GEMM: C[M,Nout] = f(A)[M,K] @ Wt[Nout,K]^T =================
// Optional fused input transform f = sigmoid(a*sc[k]+sh[k]); optional fused column stats.
template<int K, bool APPLY, bool STATS>
__global__ __launch_bounds__(256) void k_mfma(const ushort* __restrict__ A, const ushort* __restrict__ Wt,
                                              ushort* __restrict__ C, int M, int Nout,
                                              const float* __restrict__ sc, const float* __restrict__ sh,
                                              float* __restrict__ gsum, float* __restrict__ gsq) {
    int m0 = blockIdx.x * 128;
    int n0 = blockIdx.y * 64;
    int w = threadIdx.x >> 6, lane = threadIdx.x & 63;
    int wr = w >> 1, wc = w & 1;
    int rf = lane & 15;
    int kg = lane >> 4;

    const ushort* ap[4];
    #pragma unroll
    for (int mf = 0; mf < 4; ++mf) {
        int row = m0 + wr * 64 + mf * 16 + rf;
        if (row >= M) row = M - 1;                   // clamp; store/stats guarded
        ap[mf] = A + (size_t)row * K + kg * 8;
    }
    const ushort* bp[2];
    #pragma unroll
    for (int nf = 0; nf < 2; ++nf)
        bp[nf] = Wt + (size_t)(n0 + wc * 32 + nf * 16 + rf) * K + kg * 8;

    f32x4 acc[4][2];
    #pragma unroll
    for (int mf = 0; mf < 4; ++mf)
        #pragma unroll
        for (int nf = 0; nf < 2; ++nf)
            acc[mf][nf] = (f32x4){0.f, 0.f, 0.f, 0.f};

    #pragma unroll 2
    for (int kk = 0; kk < K / 32; ++kk) {
        short8 a[4], b[2];
        #pragma unroll
        for (int mf = 0; mf < 4; ++mf) {
            a[mf] = *reinterpret_cast<const short8*>(ap[mf] + kk * 32);
            if constexpr (APPLY) {
                int kbase = kk * 32 + kg * 8;
                union { short8 s; uint u[4]; } in, o;
                in.s = a[mf];
                #pragma unroll
                for (int i = 0; i < 4; ++i) {
                    int k = kbase + 2 * i;
                    float x0 = bl(in.u[i]) * sc[k] + sh[k];
                    float x1 = bh(in.u[i]) * sc[k + 1] + sh[k + 1];
                    x0 = 1.f / (1.f + __expf(-x0));
                    x1 = 1.f / (1.f + __expf(-x1));
                    o.u[i] = pack2(x0, x1);
                }
                a[mf] = o.s;
            }
        }
        #pragma unroll
        for (int nf = 0; nf < 2; ++nf)
            b[nf] = *reinterpret_cast<const short8*>(bp[nf] + kk * 32);
        #pragma unroll
        for (int mf = 0; mf < 4; ++mf)
            #pragma unroll
            for (int nf = 0; nf < 2; ++nf)
                acc[mf][nf] = __builtin_amdgcn_mfma_f32_16x16x32_bf16(a[mf], b[nf], acc[mf][nf], 0, 0, 0);
    }

    #pragma unroll
    for (int mf = 0; mf < 4; ++mf)
        #pragma unroll
        for (int nf = 0; nf < 2; ++nf) {
            int col = n0 + wc * 32 + nf * 16 + rf;
            #pragma unroll
            for (int j = 0; j < 4; ++j) {
                int row = m0 + wr * 64 + mf * 16 + kg * 4 + j;
                if (row < M) C[(size_t)row * Nout + col] = f2b(acc[mf][nf][j]);
            }
        }

    if constexpr (STATS) {
        __shared__ float bns[2][64], bnq[2][64];
        #pragma unroll
        for (int nf = 0; nf < 2; ++nf) {
            float cs = 0.f, cq = 0.f;
            #pragma unroll
            for (int mf = 0; mf < 4; ++mf)
                #pragma unroll
                for (int j = 0; j < 4; ++j) {
                    int row = m0 + wr * 64 + mf * 16 + kg * 4 + j;
                    float v = (row < M) ? acc[mf][nf][j] : 0.f;
                    cs += v; cq += v * v;
                }
            cs += __shfl_xor(cs, 16); cs += __shfl_xor(cs, 32);
            cq += __shfl_xor(cq, 16); cq += __shfl_xor(cq, 32);
            if (kg == 0) { bns[wr][wc * 32 + nf * 16 + rf] = cs; bnq[wr][wc * 32 + nf * 16 + rf] = cq; }
        }
        __syncthreads();
        int t = threadIdx.x;
        if (t < 64) {
            atomicAdd(&gsum[n0 + t], bns[0][t] + bns[1][t]);
            atomicAdd(&gsq[n0 + t],  bnq[0][t] + bnq[1][t]);
        }
    }
}

// ================= BN finalize =================
__global__ void k_bnfin(const float* __restrict__ sums, const float* __restrict__ sumsq,
                        const float* __restrict__ g, const float* __restrict__ beta,
                        float* __restrict__ scale, float* __restrict__ shift, int F, float invN) {
    int f = threadIdx.x;
    if (f < F) {
        float m = sums[f] * invN;
        float var = sumsq[f] * invN - m * m;
        float s = g[f] * rsqrtf(var + 1e-5f);
        scale[f] = s;
        shift[f] = beta[f] - m * s;
    }
}

// ================= decode: logits[e] = dot64( bn(h[a]), bn(h[b]) ) =================
__global__ __launch_bounds__(256) void k_decode(const ushort* __restrict__ h,
                                                const float* __restrict__ sc, const float* __restrict__ sh,
                                                const int* __restrict__ pos, const int* __restrict__ neg,
                                                int Pp, int Pn, float* __restrict__ out) {
    int gid = blockIdx.x * 16 + (threadIdx.x >> 4);
    int l = threadIdx.x & 15;
    int P = Pp + Pn;
    if (gid >= P) return;
    int a, b;
    if (gid < Pp) { a = pos[gid]; b = pos[Pp + gid]; }
    else          { int e = gid - Pp; a = neg[e]; b = neg[Pn + e]; }
    const uint2* hu = reinterpret_cast<const uint2*>(h);
    uint2 ua = hu[(size_t)a * 16 + l];
    uint2 ub = hu[(size_t)b * 16 + l];
    int f = l * 4;
    float s0 = sc[f], s1 = sc[f + 1], s2 = sc[f + 2], s3 = sc[f + 3];
    float t0 = sh[f], t1 = sh[f + 1], t2 = sh[f + 2], t3 = sh[f + 3];
    float a0 = bl(ua.x) * s0 + t0, a1 = bh(ua.x) * s1 + t1, a2 = bl(ua.y) * s2 + t2, a3 = bh(ua.y) * s3 + t3;
    float b0 = bl(ub.x) * s0 + t0, b1 = bh(ub.x) * s1 + t1, b2 = bl(ub.y) * s2 + t2, b3 = bh(ub.y) * s3 + t3;
    float d = a0 * b0 + a1 * b1 + a2 * b2 + a3 * b3;
    d += __shfl_xor(d, 1);
    d += __shfl_xor(d, 2);
    d += __shfl_xor(d, 4);
    d += __shfl_xor(d, 8);
    if (l == 0) out[gid] = d;
}

// ================= launch =================
extern "C" void kernel_launch(void* const* d_in, const int* in_sizes, int n_in,
                              void* d_out, int out_size, void* d_ws, size_t ws_size,
                              hipStream_t stream) {
    const float* x   = (const float*)d_in[0];
    const int*   ei  = (const int*)d_in[1];
    const int*   pe  = (const int*)d_in[2];
    const int*   ne  = (const int*)d_in[3];
    const float* W1  = (const float*)d_in[4];
    const float* g1  = (const float*)d_in[6];
    const float* be1 = (const float*)d_in[7];
    const float* W2  = (const float*)d_in[8];
    const float* g2  = (const float*)d_in[10];
    const float* be2 = (const float*)d_in[11];
    const float* W3  = (const float*)d_in[12];
    const float* g3  = (const float*)d_in[14];
    const float* be3 = (const float*)d_in[15];
    float* out = (float*)d_out;

    const int N  = in_sizes[0] / 128;
    const int E  = in_sizes[1] / 2;
    const int Pp = in_sizes[2] / 2;
    const int Pn = in_sizes[3] / 2;

    char* ws = (char*)d_ws;
    auto carve = [&](size_t bytes) -> char* {
        char* p = ws;
        ws += (bytes + 255) & ~(size_t)255;
        return p;
    };
    // zero zone: gh[256] + sums1[256]+sq1[256]+sums2[128]+sq2[128]+sums3[64]+sq3[64]
    char*  zz     = carve(256 * 4 + 896 * 4);
    int*   gh     = (int*)zz;
    float* sums1  = (float*)(zz + 1024);
    float* sq1    = sums1 + 256;
    float* sums2  = sq1 + 256;
    float* sq2    = sums2 + 128;
    float* sums3  = sq2 + 128;
    float* sq3    = sums3 + 64;
    size_t zz_bytes = 1024 + 896 * 4;

    int*    boff   = (int*)carve(257 * 4);
    int*    bcur   = (int*)carve(256 * 4);
    int*    rowptr = (int*)carve((size_t)(N + 1) * 4);
    float*  dinv   = (float*)carve((size_t)N * 4);
    int*    srcs   = (int*)carve((size_t)E * 4);
    int2*   pairs  = (int2*)carve((size_t)E * 8);
    float*  scale1 = (float*)carve(256 * 4);
    float*  shift1 = (float*)carve(256 * 4);
    float*  scale2 = (float*)carve(128 * 4);
    float*  shift2 = (float*)carve(128 * 4);
    float*  scale3 = (float*)carve(64 * 4);
    float*  shift3 = (float*)carve(64 * 4);
    ushort* Wt1    = (ushort*)carve(128 * 256 * 2);
    ushort* Wt2    = (ushort*)carve(256 * 128 * 2);
    ushort* Wt3    = (ushort*)carve(128 * 64 * 2);
    ushort* b1     = (ushort*)carve((size_t)N * 128 * 2);   // xb -> gemm2 out -> gemm3 out
    ushort* b2     = (ushort*)carve((size_t)N * 128 * 2);   // agg1 out -> agg2 out -> agg3 out
    ushort* b3     = (ushort*)carve((size_t)N * 256 * 2);   // gemm1 out (h1 raw)

    const int* e_src = ei;
    const int* e_dst = ei + E;
    const int NBUCK = (N + (1 << BSHIFT) - 1) >> BSHIFT;    // 196 for N=100000

    hipMemsetAsync(zz, 0, zz_bytes, stream);

    // ---- CSR build: binned 2-level counting sort ----
    k_bhist<<<2048, 256, 0, stream>>>(e_dst, gh, E);
    k_bscan<<<1, 256, 0, stream>>>(gh, boff, bcur);
    k_bscatter<<<(E + SCHUNK - 1) / SCHUNK, 256, 0, stream>>>(e_src, e_dst, bcur, pairs, E);
    k_bfine<<<NBUCK, 256, 0, stream>>>(pairs, boff, rowptr, srcs, dinv, N, E);

    // ---- conversions ----
    {
        size_t n4 = (size_t)N * 128 / 4;
        k_convx<<<(int)((n4 + 255) / 256), 256, 0, stream>>>(x, b1, n4);
        k_convWT<<<(128 * 256 + 255) / 256, 256, 0, stream>>>(W1, Wt1, 128, 256);
        k_convWT<<<(256 * 128 + 255) / 256, 256, 0, stream>>>(W2, Wt2, 256, 128);
        k_convWT<<<(128 * 64 + 255) / 256, 256, 0, stream>>>(W3, Wt3, 128, 64);
    }

    const int mblk = (N + 127) / 128;

    // ---- Layer 1: agg(x) -> GEMM1 (+stats) -> bnfin1 ----
    k_agg<128, false><<<2048, 256, 0, stream>>>(b1, b2, rowptr, srcs, dinv, N, nullptr, nullptr);
    { dim3 g(mblk, 4); k_mfma<128, false, true><<<g, 256, 0, stream>>>(b2, Wt1, b3, N, 256, nullptr, nullptr, sums1, sq1); }
    k_bnfin<<<1, 256, 0, stream>>>(sums1, sq1, g1, be1, scale1, shift1, 256, 1.0f / N);

    // ---- Layer 2: GEMM2 (apply bn1+sig on load) -> agg (+stats) -> bnfin2 ----
    { dim3 g(mblk, 2); k_mfma<256, true, false><<<g, 256, 0, stream>>>(b3, Wt2, b1, N, 128, scale1, shift1, nullptr, nullptr); }
    k_agg<128, true><<<2048, 256, 0, stream>>>(b1, b2, rowptr, srcs, dinv, N, sums2, sq2);
    k_bnfin<<<1, 256, 0, stream>>>(sums2, sq2, g2, be2, scale2, shift2, 128, 1.0f / N);

    // ---- Layer 3: GEMM3 (apply bn2+sig on load) -> agg (+stats) -> bnfin3 ----
    { dim3 g(mblk, 1); k_mfma<128, true, false><<<g, 256, 0, stream>>>(b2, Wt3, b1, N, 64, scale2, shift2, nullptr, nullptr); }
    k_agg<64, true><<<1024, 256, 0, stream>>>(b1, b2, rowptr, srcs, dinv, N, sums3, sq3);
    k_bnfin<<<1, 256, 0, stream>>>(sums3, sq3, g3, be3, scale3, shift3, 64, 1.0f / N);

    // ---- decode (bn3 applied on load) ----
    k_decode<<<(Pp + Pn + 15) / 16, 256, 0, stream>>>(b2, scale3, shift3, pe, ne, Pp, Pn, out);
}

// Round 4
// 580.894 us; speedup vs baseline: 1.9598x; 1.3878x over previous
//
#include <hip/hip_runtime.h>
#include <hip/hip_bf16.h>
#include <stddef.h>

// GCN link predictor: 3x (GCNConv -> BN -> [sigmoid]) then edge dot decode.
//  - CSR by dst built per call via 2-level binned counting sort (write-coalesced).
//  - bf16 activations; MFMA 16x16x32 GEMMs (no LDS, fragments direct from global).
//  - Agg: one-shot waves, 4-8 nodes/wave, uint4 row gathers (latency-bound -> max MLP).
//  - BN stats: fused in GEMM1 epilogue; separate vectorized pass after agg2/agg3.
//  - BN apply+sigmoid fused into consumer loads (GEMM2 / GEMM3 / decode).
//  - Biases cancel under training-mode BN -> skipped.

#define WAVE 64
#define BSHIFT 9                    // 512 nodes per coarse bucket (N <= 131072)
#define SCHUNK 4096                 // edges per bscatter block

typedef __attribute__((ext_vector_type(8))) short short8;
typedef __attribute__((ext_vector_type(4))) float f32x4;

__device__ __forceinline__ float bl(uint g) { return __uint_as_float(g << 16); }
__device__ __forceinline__ float bh(uint g) { return __uint_as_float(g & 0xffff0000u); }
__device__ __forceinline__ ushort f2b(float f) {           // round-to-nearest-even
    uint u = __float_as_uint(f);
    return (ushort)((u + 0x7fffu + ((u >> 16) & 1u)) >> 16);
}
__device__ __forceinline__ uint pack2(float lo, float hi) {
    return (uint)f2b(lo) | ((uint)f2b(hi) << 16);
}

// ================= binned counting sort (CSR build) =================
__global__ __launch_bounds__(256) void k_bhist(const int* __restrict__ dst, int* __restrict__ gh, int E) {
    __shared__ int lh[256];
    lh[threadIdx.x] = 0; __syncthreads();
    int i = blockIdx.x * 256 + threadIdx.x, stride = gridDim.x * 256;
    for (; i < E; i += stride) atomicAdd(&lh[dst[i] >> BSHIFT], 1);
    __syncthreads();
    int v = lh[threadIdx.x];
    if (v) atomicAdd(&gh[threadIdx.x], v);
}

__global__ void k_bscan(const int* __restrict__ gh, int* __restrict__ boff, int* __restrict__ bcur) {
    __shared__ int ls[256];
    int t = threadIdx.x;
    int v = gh[t];
    ls[t] = v; __syncthreads();
    for (int off = 1; off < 256; off <<= 1) {
        int x = (t >= off) ? ls[t - off] : 0;
        __syncthreads();
        ls[t] += x;
        __syncthreads();
    }
    int excl = ls[t] - v;
    boff[t] = excl; bcur[t] = excl;
    if (t == 255) boff[256] = ls[255];
}

__global__ __launch_bounds__(256) void k_bscatter(const int* __restrict__ src, const int* __restrict__ dst,
                                                  int* __restrict__ gcur, int2* __restrict__ pairs, int E) {
    __shared__ int lh[256];
    int t = threadIdx.x;
    int base = blockIdx.x * SCHUNK;
    lh[t] = 0; __syncthreads();
    int rs[16], rd[16];
    #pragma unroll
    for (int i = 0; i < 16; ++i) {
        int idx = base + i * 256 + t;
        if (idx < E) { rs[i] = src[idx]; rd[i] = dst[idx]; atomicAdd(&lh[rd[i] >> BSHIFT], 1); }
        else rd[i] = -1;
    }
    __syncthreads();
    int cnt_b = lh[t];
    int b0 = cnt_b ? atomicAdd(&gcur[t], cnt_b) : 0;
    lh[t] = b0;
    __syncthreads();
    #pragma unroll
    for (int i = 0; i < 16; ++i) {
        if (rd[i] >= 0) {
            int p = atomicAdd(&lh[rd[i] >> BSHIFT], 1);
            pairs[p] = make_int2(rs[i], rd[i]);
        }
    }
}

// per-bucket: fine counting sort; also emits rowptr + dinv
__global__ __launch_bounds__(256) void k_bfine(const int2* __restrict__ pairs, const int* __restrict__ boff,
                                               int* __restrict__ rowptr, int* __restrict__ srcs,
                                               float* __restrict__ dinv, int N, int E) {
    __shared__ int lcnt[512];
    __shared__ int ls[256];
    int b = blockIdx.x, t = threadIdx.x;
    int d0 = b << BSHIFT;
    int e0 = boff[b], e1 = boff[b + 1];
    lcnt[t] = 0; lcnt[t + 256] = 0;
    __syncthreads();
    for (int e = e0 + t; e < e1; e += 256)
        atomicAdd(&lcnt[pairs[e].y - d0], 1);
    __syncthreads();
    int c0 = lcnt[2 * t], c1 = lcnt[2 * t + 1];
    ls[t] = c0 + c1;
    __syncthreads();
    for (int off = 1; off < 256; off <<= 1) {
        int x = (t >= off) ? ls[t - off] : 0;
        __syncthreads();
        ls[t] += x;
        __syncthreads();
    }
    int excl = ls[t] - (c0 + c1);
    int s0 = excl, s1 = excl + c0;
    int d = d0 + 2 * t;
    if (d < N)     { rowptr[d] = e0 + s0;     dinv[d] = rsqrtf((float)(c0 + 1)); }
    if (d + 1 < N) { rowptr[d + 1] = e0 + s1; dinv[d + 1] = rsqrtf((float)(c1 + 1)); }
    if (b == 0 && t == 0) rowptr[N] = E;
    lcnt[2 * t] = s0; lcnt[2 * t + 1] = s1;
    __syncthreads();
    for (int e = e0 + t; e < e1; e += 256) {
        int2 p = pairs[e];
        int pos = atomicAdd(&lcnt[p.y - d0], 1);
        srcs[e0 + pos] = p.x;
    }
}

// ================= conversions =================
__global__ void k_convx(const float* __restrict__ in, ushort* __restrict__ out, size_t n4) {
    size_t i = (size_t)blockIdx.x * blockDim.x + threadIdx.x;
    if (i >= n4) return;
    float4 v = reinterpret_cast<const float4*>(in)[i];
    uint2 o;
    o.x = pack2(v.x, v.y);
    o.y = pack2(v.z, v.w);
    reinterpret_cast<uint2*>(out)[i] = o;
}

// Wt[n*K + k] = bf16(W[k*N + n])
__global__ void k_convWT(const float* __restrict__ W, ushort* __restrict__ Wt, int K, int N) {
    int i = blockIdx.x * blockDim.x + threadIdx.x;
    if (i >= K * N) return;
    int k = i / N, n = i % N;
    Wt[(size_t)n * K + k] = f2b(W[i]);
}

// ================= aggregation: out[i] = dinv[i]*( sum_e dinv[s]*in[s] + dinv[i]*in[i] ) =================
// One-shot waves; L = row bytes/16 lanes per node; G = 64/L nodes per wave (independent chains -> MLP).
template<int F>
__global__ __launch_bounds__(256) void k_agg(const ushort* __restrict__ in, ushort* __restrict__ out,
                                             const int* __restrict__ rowptr, const int* __restrict__ srcs,
                                             const float* __restrict__ dinv, int N) {
    constexpr int L = (F * 2) / 16;          // lanes per node (uint4 = 16B each)
    int wv = threadIdx.x >> 6, lane = threadIdx.x & 63;
    int node = (blockIdx.x * 4 + wv) * (64 / L) + lane / L;
    int sl = lane % L;
    if (node >= N) return;
    const uint4* inq = reinterpret_cast<const uint4*>(in);
    float di = dinv[node];
    float acc[8];
    {
        uint4 v = inq[(size_t)node * L + sl];
        acc[0] = di * bl(v.x); acc[1] = di * bh(v.x);
        acc[2] = di * bl(v.y); acc[3] = di * bh(v.y);
        acc[4] = di * bl(v.z); acc[5] = di * bh(v.z);
        acc[6] = di * bl(v.w); acc[7] = di * bh(v.w);
    }
    int e = rowptr[node], e1 = rowptr[node + 1];
    for (; e + 1 < e1; e += 2) {
        int s0 = srcs[e], s1 = srcs[e + 1];
        float d0 = dinv[s0], d1 = dinv[s1];
        uint4 v0 = inq[(size_t)s0 * L + sl];
        uint4 v1 = inq[(size_t)s1 * L + sl];
        acc[0] += d0 * bl(v0.x) + d1 * bl(v1.x);
        acc[1] += d0 * bh(v0.x) + d1 * bh(v1.x);
        acc[2] += d0 * bl(v0.y) + d1 * bl(v1.y);
        acc[3] += d0 * bh(v0.y) + d1 * bh(v1.y);
        acc[4] += d0 * bl(v0.z) + d1 * bl(v1.z);
        acc[5] += d0 * bh(v0.z) + d1 * bh(v1.z);
        acc[6] += d0 * bl(v0.w) + d1 * bl(v1.w);
        acc[7] += d0 * bh(v0.w) + d1 * bh(v1.w);
    }
    if (e < e1) {
        int s0 = srcs[e];
        float d0 = dinv[s0];
        uint4 v0 = inq[(size_t)s0 * L + sl];
        acc[0] += d0 * bl(v0.x); acc[1] += d0 * bh(v0.x);
        acc[2] += d0 * bl(v0.y); acc[3] += d0 * bh(v0.y);
        acc[4] += d0 * bl(v0.z); acc[5] += d0 * bh(v0.z);
        acc[6] += d0 * bl(v0.w); acc[7] += d0 * bh(v0.w);
    }
    uint4 o;
    o.x = pack2(acc[0] * di, acc[1] * di);
    o.y = pack2(acc[2] * di, acc[3] * di);
    o.z = pack2(acc[4] * di, acc[5] * di);
    o.w = pack2(acc[6] * di, acc[7] * di);
    reinterpret_cast<uint4*>(out)[(size_t)node * L + sl] = o;
}

// ================= vectorized BN stats (streaming, bf16 uint4 loads) =================
template<int F>
__global__ __launch_bounds__(256) void k_bnstats(const ushort* __restrict__ h, float* __restrict__ gsum,
                                                 float* __restrict__ gsq, int N) {
    constexpr int C = F / 8;                 // uint4 chunks per row (16 or 8)
    constexpr int RPW = 64 / C;              // rows per wave per step
    __shared__ float ls[4][16][16];          // [wave][chunk][0..7 sum, 8..15 sq]
    int wv = threadIdx.x >> 6, lane = threadIdx.x & 63;
    int fidx = lane % C, rsub = lane / C;
    int row = (blockIdx.x * 4 + wv) * RPW + rsub;
    int rstride = gridDim.x * 4 * RPW;
    const uint4* hq = reinterpret_cast<const uint4*>(h);
    float s[8] = {}, q[8] = {};
    for (int r = row; r < N; r += rstride) {
        uint4 v = hq[(size_t)r * C + fidx];
        float x;
        x = bl(v.x); s[0] += x; q[0] += x * x;
        x = bh(v.x); s[1] += x; q[1] += x * x;
        x = bl(v.y); s[2] += x; q[2] += x * x;
        x = bh(v.y); s[3] += x; q[3] += x * x;
        x = bl(v.z); s[4] += x; q[4] += x * x;
        x = bh(v.z); s[5] += x; q[5] += x * x;
        x = bl(v.w); s[6] += x; q[6] += x * x;
        x = bh(v.w); s[7] += x; q[7] += x * x;
    }
    #pragma unroll
    for (int m = C; m < 64; m <<= 1) {
        #pragma unroll
        for (int j = 0; j < 8; ++j) { s[j] += __shfl_xor(s[j], m); q[j] += __shfl_xor(q[j], m); }
    }
    if (lane < C) {
        #pragma unroll
        for (int j = 0; j < 8; ++j) { ls[wv][lane][j] = s[j]; ls[wv][lane][8 + j] = q[j]; }
    }
    __syncthreads();
    int t = threadIdx.x;
    if (t < F) {
        int ch = t / 8, j = t % 8;
        float S = 0.f, Q = 0.f;
        #pragma unroll
        for (int w = 0; w < 4; ++w) { S += ls[w][ch][j]; Q += ls[w][ch][8 + j]; }
        atomicAdd(&gsum[t], S); atomicAdd(&gsq[t], Q);
    }
}

// ================= MFMA bf16 GEMM: C[M,Nout] = f(A)[M,K] @ Wt[Nout,K]^T =================
// Block: 128 rows x NF*32 cols, 4 waves (2x2); wave tile 64 x NF*16.
// Optional fused input transform f = sigmoid(a*sc[k]+sh[k]); optional fused column stats.
template<int K, int NF, bool APPLY, bool STATS>
__global__ __launch_bounds__(256) void k_mfma(const ushort* __restrict__ A, const ushort* __restrict__ Wt,
                                              ushort* __restrict__ C, int M, int Nout,
                                              const float* __restrict__ sc, const float* __restrict__ sh,
                                              float* __restrict__ gsum, float* __restrict__ gsq) {
    int m0 = blockIdx.x * 128;
    int n0 = blockIdx.y * (NF * 32);
    int w = threadIdx.x >> 6, lane = threadIdx.x & 63;
    int wr = w >> 1, wc = w & 1;
    int rf = lane & 15;
    int kg = lane >> 4;

    const ushort* ap[4];
    #pragma unroll
    for (int mf = 0; mf < 4; ++mf) {
        int row = m0 + wr * 64 + mf * 16 + rf;
        if (row >= M) row = M - 1;                   // clamp; store/stats guarded
        ap[mf] = A + (size_t)row * K + kg * 8;
    }
    const ushort* bp[NF];
    #pragma unroll
    for (int nf = 0; nf < NF; ++nf)
        bp[nf] = Wt + (size_t)(n0 + wc * (NF * 16) + nf * 16 + rf) * K + kg * 8;

    f32x4 acc[4][NF];
    #pragma unroll
    for (int mf = 0; mf < 4; ++mf)
        #pragma unroll
        for (int nf = 0; nf < NF; ++nf)
            acc[mf][nf] = (f32x4){0.f, 0.f, 0.f, 0.f};

    #pragma unroll 2
    for (int kk = 0; kk < K / 32; ++kk) {
        short8 a[4], b[NF];
        #pragma unroll
        for (int mf = 0; mf < 4; ++mf) {
            a[mf] = *reinterpret_cast<const short8*>(ap[mf] + kk * 32);
            if constexpr (APPLY) {
                int kbase = kk * 32 + kg * 8;
                union { short8 s; uint u[4]; } in, o;
                in.s = a[mf];
                #pragma unroll
                for (int i = 0; i < 4; ++i) {
                    int k = kbase + 2 * i;
                    float x0 = bl(in.u[i]) * sc[k] + sh[k];
                    float x1 = bh(in.u[i]) * sc[k + 1] + sh[k + 1];
                    x0 = 1.f / (1.f + __expf(-x0));
                    x1 = 1.f / (1.f + __expf(-x1));
                    o.u[i] = pack2(x0, x1);
                }
                a[mf] = o.s;
            }
        }
        #pragma unroll
        for (int nf = 0; nf < NF; ++nf)
            b[nf] = *reinterpret_cast<const short8*>(bp[nf] + kk * 32);
        #pragma unroll
        for (int mf = 0; mf < 4; ++mf)
            #pragma unroll
            for (int nf = 0; nf < NF; ++nf)
                acc[mf][nf] = __builtin_amdgcn_mfma_f32_16x16x32_bf16(a[mf], b[nf], acc[mf][nf], 0, 0, 0);
    }

    #pragma unroll
    for (int mf = 0; mf < 4; ++mf)
        #pragma unroll
        for (int nf = 0; nf < NF; ++nf) {
            int col = n0 + wc * (NF * 16) + nf * 16 + rf;
            #pragma unroll
            for (int j = 0; j < 4; ++j) {
                int row = m0 + wr * 64 + mf * 16 + kg * 4 + j;
                if (row < M) C[(size_t)row * Nout + col] = f2b(acc[mf][nf][j]);
            }
        }

    if constexpr (STATS) {
        __shared__ float bns[2][NF * 32], bnq[2][NF * 32];
        #pragma unroll
        for (int nf = 0; nf < NF; ++nf) {
            float cs = 0.f, cq = 0.f;
            #pragma unroll
            for (int mf = 0; mf < 4; ++mf)
                #pragma unroll
                for (int j = 0; j < 4; ++j) {
                    int row = m0 + wr * 64 + mf * 16 + kg * 4 + j;
                    float v = (row < M) ? acc[mf][nf][j] : 0.f;
                    cs += v; cq += v * v;
                }
            cs += __shfl_xor(cs, 16); cs += __shfl_xor(cs, 32);
            cq += __shfl_xor(cq, 16); cq += __shfl_xor(cq, 32);
            if (kg == 0) { bns[wr][wc * (NF * 16) + nf * 16 + rf] = cs; bnq[wr][wc * (NF * 16) + nf * 16 + rf] = cq; }
        }
        __syncthreads();
        int t = threadIdx.x;
        if (t < NF * 32) {
            atomicAdd(&gsum[n0 + t], bns[0][t] + bns[1][t]);
            atomicAdd(&gsq[n0 + t],  bnq[0][t] + bnq[1][t]);
        }
    }
}

// ================= BN finalize =================
__global__ void k_bnfin(const float* __restrict__ sums, const float* __restrict__ sumsq,
                        const float* __restrict__ g, const float* __restrict__ beta,
                        float* __restrict__ scale, float* __restrict__ shift, int F, float invN) {
    int f = threadIdx.x;
    if (f < F) {
        float m = sums[f] * invN;
        float var = sumsq[f] * invN - m * m;
        float s = g[f] * rsqrtf(var + 1e-5f);
        scale[f] = s;
        shift[f] = beta[f] - m * s;
    }
}

// ================= decode: logits[e] = dot64( bn(h[a]), bn(h[b]) ) =================
__global__ __launch_bounds__(256) void k_decode(const ushort* __restrict__ h,
                                                const float* __restrict__ sc, const float* __restrict__ sh,
                                                const int* __restrict__ pos, const int* __restrict__ neg,
                                                int Pp, int Pn, float* __restrict__ out) {
    int gid = blockIdx.x * 16 + (threadIdx.x >> 4);
    int l = threadIdx.x & 15;
    int P = Pp + Pn;
    if (gid >= P) return;
    int a, b;
    if (gid < Pp) { a = pos[gid]; b = pos[Pp + gid]; }
    else          { int e = gid - Pp; a = neg[e]; b = neg[Pn + e]; }
    const uint2* hu = reinterpret_cast<const uint2*>(h);
    uint2 ua = hu[(size_t)a * 16 + l];
    uint2 ub = hu[(size_t)b * 16 + l];
    int f = l * 4;
    float s0 = sc[f], s1 = sc[f + 1], s2 = sc[f + 2], s3 = sc[f + 3];
    float t0 = sh[f], t1 = sh[f + 1], t2 = sh[f + 2], t3 = sh[f + 3];
    float a0 = bl(ua.x) * s0 + t0, a1 = bh(ua.x) * s1 + t1, a2 = bl(ua.y) * s2 + t2, a3 = bh(ua.y) * s3 + t3;
    float b0 = bl(ub.x) * s0 + t0, b1 = bh(ub.x) * s1 + t1, b2 = bl(ub.y) * s2 + t2, b3 = bh(ub.y) * s3 + t3;
    float d = a0 * b0 + a1 * b1 + a2 * b2 + a3 * b3;
    d += __shfl_xor(d, 1);
    d += __shfl_xor(d, 2);
    d += __shfl_xor(d, 4);
    d += __shfl_xor(d, 8);
    if (l == 0) out[gid] = d;
}

// ================= launch =================
extern "C" void kernel_launch(void* const* d_in, const int* in_sizes, int n_in,
                              void* d_out, int out_size, void* d_ws, size_t ws_size,
                              hipStream_t stream) {
    const float* x   = (const float*)d_in[0];
    const int*   ei  = (const int*)d_in[1];
    const int*   pe  = (const int*)d_in[2];
    const int*   ne  = (const int*)d_in[3];
    const float* W1  = (const float*)d_in[4];
    const float* g1  = (const float*)d_in[6];
    const float* be1 = (const float*)d_in[7];
    const float* W2  = (const float*)d_in[8];
    const float* g2  = (const float*)d_in[10];
    const float* be2 = (const float*)d_in[11];
    const float* W3  = (const float*)d_in[12];
    const float* g3  = (const float*)d_in[14];
    const float* be3 = (const float*)d_in[15];
    float* out = (float*)d_out;

    const int N  = in_sizes[0] / 128;
    const int E  = in_sizes[1] / 2;
    const int Pp = in_sizes[2] / 2;
    const int Pn = in_sizes[3] / 2;

    char* ws = (char*)d_ws;
    auto carve = [&](size_t bytes) -> char* {
        char* p = ws;
        ws += (bytes + 255) & ~(size_t)255;
        return p;
    };
    // zero zone: gh[256] + sums1[256]+sq1[256]+sums2[128]+sq2[128]+sums3[64]+sq3[64]
    char*  zz     = carve(256 * 4 + 896 * 4);
    int*   gh     = (int*)zz;
    float* sums1  = (float*)(zz + 1024);
    float* sq1    = sums1 + 256;
    float* sums2  = sq1 + 256;
    float* sq2    = sums2 + 128;
    float* sums3  = sq2 + 128;
    float* sq3    = sums3 + 64;
    size_t zz_bytes = 1024 + 896 * 4;

    int*    boff   = (int*)carve(257 * 4);
    int*    bcur   = (int*)carve(256 * 4);
    int*    rowptr = (int*)carve((size_t)(N + 1) * 4);
    float*  dinv   = (float*)carve((size_t)N * 4);
    int*    srcs   = (int*)carve((size_t)E * 4);
    int2*   pairs  = (int2*)carve((size_t)E * 8);
    float*  scale1 = (float*)carve(256 * 4);
    float*  shift1 = (float*)carve(256 * 4);
    float*  scale2 = (float*)carve(128 * 4);
    float*  shift2 = (float*)carve(128 * 4);
    float*  scale3 = (float*)carve(64 * 4);
    float*  shift3 = (float*)carve(64 * 4);
    ushort* Wt1    = (ushort*)carve(128 * 256 * 2);
    ushort* Wt2    = (ushort*)carve(256 * 128 * 2);
    ushort* Wt3    = (ushort*)carve(128 * 64 * 2);
    ushort* b1     = (ushort*)carve((size_t)N * 128 * 2);   // xb -> gemm2 out -> gemm3 out
    ushort* b2     = (ushort*)carve((size_t)N * 128 * 2);   // agg outs
    ushort* b3     = (ushort*)carve((size_t)N * 256 * 2);   // gemm1 out (h1 raw)

    const int* e_src = ei;
    const int* e_dst = ei + E;
    const int NBUCK = (N + (1 << BSHIFT) - 1) >> BSHIFT;

    hipMemsetAsync(zz, 0, zz_bytes, stream);

    // ---- CSR build: binned 2-level counting sort ----
    k_bhist<<<2048, 256, 0, stream>>>(e_dst, gh, E);
    k_bscan<<<1, 256, 0, stream>>>(gh, boff, bcur);
    k_bscatter<<<(E + SCHUNK - 1) / SCHUNK, 256, 0, stream>>>(e_src, e_dst, bcur, pairs, E);
    k_bfine<<<NBUCK, 256, 0, stream>>>(pairs, boff, rowptr, srcs, dinv, N, E);

    // ---- conversions ----
    {
        size_t n4 = (size_t)N * 128 / 4;
        k_convx<<<(int)((n4 + 255) / 256), 256, 0, stream>>>(x, b1, n4);
        k_convWT<<<(128 * 256 + 255) / 256, 256, 0, stream>>>(W1, Wt1, 128, 256);
        k_convWT<<<(256 * 128 + 255) / 256, 256, 0, stream>>>(W2, Wt2, 256, 128);
        k_convWT<<<(128 * 64 + 255) / 256, 256, 0, stream>>>(W3, Wt3, 128, 64);
    }

    const int mblk = (N + 127) / 128;
    const int agg128 = (N + 15) / 16;     // 4 nodes/wave * 4 waves
    const int agg64  = (N + 31) / 32;     // 8 nodes/wave * 4 waves

    // ---- Layer 1: agg(x) -> GEMM1 (+stats, 128-col blocks) -> bnfin1 ----
    k_agg<128><<<agg128, 256, 0, stream>>>(b1, b2, rowptr, srcs, dinv, N);
    { dim3 g(mblk, 2); k_mfma<128, 4, false, true><<<g, 256, 0, stream>>>(b2, Wt1, b3, N, 256, nullptr, nullptr, sums1, sq1); }
    k_bnfin<<<1, 256, 0, stream>>>(sums1, sq1, g1, be1, scale1, shift1, 256, 1.0f / N);

    // ---- Layer 2: GEMM2 (apply bn1+sig on load) -> agg -> stats -> bnfin2 ----
    { dim3 g(mblk, 1); k_mfma<256, 4, true, false><<<g, 256, 0, stream>>>(b3, Wt2, b1, N, 128, scale1, shift1, nullptr, nullptr); }
    k_agg<128><<<agg128, 256, 0, stream>>>(b1, b2, rowptr, srcs, dinv, N);
    k_bnstats<128><<<512, 256, 0, stream>>>(b2, sums2, sq2, N);
    k_bnfin<<<1, 256, 0, stream>>>(sums2, sq2, g2, be2, scale2, shift2, 128, 1.0f / N);

    // ---- Layer 3: GEMM3 (apply bn2+sig on load) -> agg -> stats -> bnfin3 ----
    { dim3 g(mblk, 1); k_mfma<128, 2, true, false><<<g, 256, 0, stream>>>(b2, Wt3, b1, N, 64, scale2, shift2, nullptr, nullptr); }
    k_agg<64><<<agg64, 256, 0, stream>>>(b1, b2, rowptr, srcs, dinv, N);
    k_bnstats<64><<<512, 256, 0, stream>>>(b2, sums3, sq3, N);
    k_bnfin<<<1, 256, 0, stream>>>(sums3, sq3, g3, be3, scale3, shift3, 64, 1.0f / N);

    // ---- decode (bn3 applied on load) ----
    k_decode<<<(Pp + Pn + 15) / 16, 256, 0, stream>>>(b2, scale3, shift3, pe, ne, Pp, Pn, out);
}

// Round 5
// 549.659 us; speedup vs baseline: 2.0712x; 1.0568x over previous
//
#include <hip/hip_runtime.h>
#include <hip/hip_bf16.h>
#include <stddef.h>

// GCN link predictor: 3x (GCNConv -> BN -> [sigmoid]) then edge dot decode.
//  - CSR by dst built per call via 2-level binned counting sort (write-coalesced).
//  - bf16 activations; MFMA 16x16x32 GEMMs, LDS-staged A (BK=64, XOR-swizzled,
//    reg-prefetch of next K-step), B fragments direct from global (L1/L2-hot).
//  - BN apply+sigmoid fused into GEMM A-staging (applied once per element).
//  - BN stats fused in GEMM1 epilogue; streaming pass after agg2/agg3.
//  - Biases cancel under training-mode BN -> skipped.

#define WAVE 64
#define BSHIFT 9                    // 512 nodes per coarse bucket (N <= 131072)
#define SCHUNK 4096                 // edges per bscatter block

typedef __attribute__((ext_vector_type(8))) short short8;
typedef __attribute__((ext_vector_type(4))) float f32x4;

__device__ __forceinline__ float bl(uint g) { return __uint_as_float(g << 16); }
__device__ __forceinline__ float bh(uint g) { return __uint_as_float(g & 0xffff0000u); }
__device__ __forceinline__ ushort f2b(float f) {           // round-to-nearest-even
    uint u = __float_as_uint(f);
    return (ushort)((u + 0x7fffu + ((u >> 16) & 1u)) >> 16);
}
__device__ __forceinline__ uint pack2(float lo, float hi) {
    return (uint)f2b(lo) | ((uint)f2b(hi) << 16);
}

// ================= binned counting sort (CSR build) =================
__global__ __launch_bounds__(256) void k_bhist(const int* __restrict__ dst, int* __restrict__ gh, int E) {
    __shared__ int lh[256];
    lh[threadIdx.x] = 0; __syncthreads();
    int i = blockIdx.x * 256 + threadIdx.x, stride = gridDim.x * 256;
    for (; i < E; i += stride) atomicAdd(&lh[dst[i] >> BSHIFT], 1);
    __syncthreads();
    int v = lh[threadIdx.x];
    if (v) atomicAdd(&gh[threadIdx.x], v);
}

__global__ void k_bscan(const int* __restrict__ gh, int* __restrict__ boff, int* __restrict__ bcur) {
    __shared__ int ls[256];
    int t = threadIdx.x;
    int v = gh[t];
    ls[t] = v; __syncthreads();
    for (int off = 1; off < 256; off <<= 1) {
        int x = (t >= off) ? ls[t - off] : 0;
        __syncthreads();
        ls[t] += x;
        __syncthreads();
    }
    int excl = ls[t] - v;
    boff[t] = excl; bcur[t] = excl;
    if (t == 255) boff[256] = ls[255];
}

__global__ __launch_bounds__(256) void k_bscatter(const int* __restrict__ src, const int* __restrict__ dst,
                                                  int* __restrict__ gcur, int2* __restrict__ pairs, int E) {
    __shared__ int lh[256];
    int t = threadIdx.x;
    int base = blockIdx.x * SCHUNK;
    lh[t] = 0; __syncthreads();
    int rs[16], rd[16];
    #pragma unroll
    for (int i = 0; i < 16; ++i) {
        int idx = base + i * 256 + t;
        if (idx < E) { rs[i] = src[idx]; rd[i] = dst[idx]; atomicAdd(&lh[rd[i] >> BSHIFT], 1); }
        else rd[i] = -1;
    }
    __syncthreads();
    int cnt_b = lh[t];
    int b0 = cnt_b ? atomicAdd(&gcur[t], cnt_b) : 0;
    lh[t] = b0;
    __syncthreads();
    #pragma unroll
    for (int i = 0; i < 16; ++i) {
        if (rd[i] >= 0) {
            int p = atomicAdd(&lh[rd[i] >> BSHIFT], 1);
            pairs[p] = make_int2(rs[i], rd[i]);
        }
    }
}

// per-bucket: fine counting sort; also emits rowptr + dinv
__global__ __launch_bounds__(256) void k_bfine(const int2* __restrict__ pairs, const int* __restrict__ boff,
                                               int* __restrict__ rowptr, int* __restrict__ srcs,
                                               float* __restrict__ dinv, int N, int E) {
    __shared__ int lcnt[512];
    __shared__ int ls[256];
    int b = blockIdx.x, t = threadIdx.x;
    int d0 = b << BSHIFT;
    int e0 = boff[b], e1 = boff[b + 1];
    lcnt[t] = 0; lcnt[t + 256] = 0;
    __syncthreads();
    for (int e = e0 + t; e < e1; e += 256)
        atomicAdd(&lcnt[pairs[e].y - d0], 1);
    __syncthreads();
    int c0 = lcnt[2 * t], c1 = lcnt[2 * t + 1];
    ls[t] = c0 + c1;
    __syncthreads();
    for (int off = 1; off < 256; off <<= 1) {
        int x = (t >= off) ? ls[t - off] : 0;
        __syncthreads();
        ls[t] += x;
        __syncthreads();
    }
    int excl = ls[t] - (c0 + c1);
    int s0 = excl, s1 = excl + c0;
    int d = d0 + 2 * t;
    if (d < N)     { rowptr[d] = e0 + s0;     dinv[d] = rsqrtf((float)(c0 + 1)); }
    if (d + 1 < N) { rowptr[d + 1] = e0 + s1; dinv[d + 1] = rsqrtf((float)(c1 + 1)); }
    if (b == 0 && t == 0) rowptr[N] = E;
    lcnt[2 * t] = s0; lcnt[2 * t + 1] = s1;
    __syncthreads();
    for (int e = e0 + t; e < e1; e += 256) {
        int2 p = pairs[e];
        int pos = atomicAdd(&lcnt[p.y - d0], 1);
        srcs[e0 + pos] = p.x;
    }
}

// ================= conversions =================
__global__ void k_convx(const float* __restrict__ in, ushort* __restrict__ out, size_t n4) {
    size_t i = (size_t)blockIdx.x * blockDim.x + threadIdx.x;
    if (i >= n4) return;
    float4 v = reinterpret_cast<const float4*>(in)[i];
    uint2 o;
    o.x = pack2(v.x, v.y);
    o.y = pack2(v.z, v.w);
    reinterpret_cast<uint2*>(out)[i] = o;
}

// Wt[n*K + k] = bf16(W[k*N + n])
__global__ void k_convWT(const float* __restrict__ W, ushort* __restrict__ Wt, int K, int N) {
    int i = blockIdx.x * blockDim.x + threadIdx.x;
    if (i >= K * N) return;
    int k = i / N, n = i % N;
    Wt[(size_t)n * K + k] = f2b(W[i]);
}

// ================= aggregation: out[i] = dinv[i]*( sum_e dinv[s]*in[s] + dinv[i]*in[i] ) =================
template<int F>
__global__ __launch_bounds__(256) void k_agg(const ushort* __restrict__ in, ushort* __restrict__ out,
                                             const int* __restrict__ rowptr, const int* __restrict__ srcs,
                                             const float* __restrict__ dinv, int N) {
    constexpr int L = (F * 2) / 16;          // lanes per node (uint4 = 16B each)
    int wv = threadIdx.x >> 6, lane = threadIdx.x & 63;
    int node = (blockIdx.x * 4 + wv) * (64 / L) + lane / L;
    int sl = lane % L;
    if (node >= N) return;
    const uint4* inq = reinterpret_cast<const uint4*>(in);
    float di = dinv[node];
    float acc[8];
    {
        uint4 v = inq[(size_t)node * L + sl];
        acc[0] = di * bl(v.x); acc[1] = di * bh(v.x);
        acc[2] = di * bl(v.y); acc[3] = di * bh(v.y);
        acc[4] = di * bl(v.z); acc[5] = di * bh(v.z);
        acc[6] = di * bl(v.w); acc[7] = di * bh(v.w);
    }
    int e = rowptr[node], e1 = rowptr[node + 1];
    for (; e + 1 < e1; e += 2) {
        int s0 = srcs[e], s1 = srcs[e + 1];
        float d0 = dinv[s0], d1 = dinv[s1];
        uint4 v0 = inq[(size_t)s0 * L + sl];
        uint4 v1 = inq[(size_t)s1 * L + sl];
        acc[0] += d0 * bl(v0.x) + d1 * bl(v1.x);
        acc[1] += d0 * bh(v0.x) + d1 * bh(v1.x);
        acc[2] += d0 * bl(v0.y) + d1 * bl(v1.y);
        acc[3] += d0 * bh(v0.y) + d1 * bh(v1.y);
        acc[4] += d0 * bl(v0.z) + d1 * bl(v1.z);
        acc[5] += d0 * bh(v0.z) + d1 * bh(v1.z);
        acc[6] += d0 * bl(v0.w) + d1 * bl(v1.w);
        acc[7] += d0 * bh(v0.w) + d1 * bh(v1.w);
    }
    if (e < e1) {
        int s0 = srcs[e];
        float d0 = dinv[s0];
        uint4 v0 = inq[(size_t)s0 * L + sl];
        acc[0] += d0 * bl(v0.x); acc[1] += d0 * bh(v0.x);
        acc[2] += d0 * bl(v0.y); acc[3] += d0 * bh(v0.y);
        acc[4] += d0 * bl(v0.z); acc[5] += d0 * bh(v0.z);
        acc[6] += d0 * bl(v0.w); acc[7] += d0 * bh(v0.w);
    }
    uint4 o;
    o.x = pack2(acc[0] * di, acc[1] * di);
    o.y = pack2(acc[2] * di, acc[3] * di);
    o.z = pack2(acc[4] * di, acc[5] * di);
    o.w = pack2(acc[6] * di, acc[7] * di);
    reinterpret_cast<uint4*>(out)[(size_t)node * L + sl] = o;
}

// ================= vectorized BN stats (streaming, bf16 uint4 loads) =================
template<int F>
__global__ __launch_bounds__(256) void k_bnstats(const ushort* __restrict__ h, float* __restrict__ gsum,
                                                 float* __restrict__ gsq, int N) {
    constexpr int C = F / 8;                 // uint4 chunks per row (16 or 8)
    constexpr int RPW = 64 / C;              // rows per wave per step
    __shared__ float ls[4][16][16];          // [wave][chunk][0..7 sum, 8..15 sq]
    int wv = threadIdx.x >> 6, lane = threadIdx.x & 63;
    int fidx = lane % C, rsub = lane / C;
    int row = (blockIdx.x * 4 + wv) * RPW + rsub;
    int rstride = gridDim.x * 4 * RPW;
    const uint4* hq = reinterpret_cast<const uint4*>(h);
    float s[8] = {}, q[8] = {};
    for (int r = row; r < N; r += rstride) {
        uint4 v = hq[(size_t)r * C + fidx];
        float x;
        x = bl(v.x); s[0] += x; q[0] += x * x;
        x = bh(v.x); s[1] += x; q[1] += x * x;
        x = bl(v.y); s[2] += x; q[2] += x * x;
        x = bh(v.y); s[3] += x; q[3] += x * x;
        x = bl(v.z); s[4] += x; q[4] += x * x;
        x = bh(v.z); s[5] += x; q[5] += x * x;
        x = bl(v.w); s[6] += x; q[6] += x * x;
        x = bh(v.w); s[7] += x; q[7] += x * x;
    }
    #pragma unroll
    for (int m = C; m < 64; m <<= 1) {
        #pragma unroll
        for (int j = 0; j < 8; ++j) { s[j] += __shfl_xor(s[j], m); q[j] += __shfl_xor(q[j], m); }
    }
    if (lane < C) {
        #pragma unroll
        for (int j = 0; j < 8; ++j) { ls[wv][lane][j] = s[j]; ls[wv][lane][8 + j] = q[j]; }
    }
    __syncthreads();
    int t = threadIdx.x;
    if (t < F) {
        int ch = t / 8, j = t % 8;
        float S = 0.f, Q = 0.f;
        #pragma unroll
        for (int w = 0; w < 4; ++w) { S += ls[w][ch][j]; Q += ls[w][ch][8 + j]; }
        atomicAdd(&gsum[t], S); atomicAdd(&gsq[t], Q);
    }
}

// ================= MFMA bf16 GEMM: C[M,Nout] = f(A)[M,K] @ Wt[Nout,K]^T =================
// BM=128, BK=64, 4 waves (2x2); wave tile 64 x NF*16. A staged in LDS (XOR chunk
// swizzle), next K-step reg-prefetched. f = sigmoid(a*sc[k]+sh[k]) applied at staging.
template<int K, int NF, bool APPLY, bool STATS>
__global__ __launch_bounds__(256) void k_mfma(const ushort* __restrict__ A, const ushort* __restrict__ Wt,
                                              ushort* __restrict__ C, int M, int Nout,
                                              const float* __restrict__ sc, const float* __restrict__ sh,
                                              float* __restrict__ gsum, float* __restrict__ gsq) {
    constexpr int S = K / 64;                 // K-steps
    __shared__ uint4 Alds[128 * 8];           // 128 rows x 8 swizzled 16B chunks = 16KB
    __shared__ float scl[K], shl[K];
    int m0 = blockIdx.x * 128;
    int n0 = blockIdx.y * (NF * 32);
    int t = threadIdx.x;
    int w = t >> 6, lane = t & 63;
    int wr = w >> 1, wc = w & 1;
    int rf = lane & 15, kg = lane >> 4;

    if (APPLY) {
        for (int i = t; i < K; i += 256) { scl[i] = sc[i]; shl[i] = sh[i]; }
    }

    // staging map: thread t covers chunks t, t+256, t+512, t+768 (chunk = row*8 + c)
    int srow[4], schk[4];
    const ushort* sga[4];
    #pragma unroll
    for (int i = 0; i < 4; ++i) {
        int chunk = t + i * 256;
        int r = chunk >> 3, c = chunk & 7;
        srow[i] = r; schk[i] = c;
        int gr = m0 + r; if (gr >= M) gr = M - 1;   // clamp; store/stats guarded
        sga[i] = A + (size_t)gr * K + c * 8;
    }
    uint4 regs[4];
    #pragma unroll
    for (int i = 0; i < 4; ++i) regs[i] = *reinterpret_cast<const uint4*>(sga[i]);

    const ushort* bp[NF];
    #pragma unroll
    for (int nf = 0; nf < NF; ++nf)
        bp[nf] = Wt + (size_t)(n0 + wc * (NF * 16) + nf * 16 + rf) * K + kg * 8;

    f32x4 acc[4][NF];
    #pragma unroll
    for (int mf = 0; mf < 4; ++mf)
        #pragma unroll
        for (int nf = 0; nf < NF; ++nf)
            acc[mf][nf] = (f32x4){0.f, 0.f, 0.f, 0.f};

    if (APPLY) __syncthreads();               // scl/shl visible

    for (int s = 0; s < S; ++s) {
        // transform + write current regs to LDS (swizzled)
        #pragma unroll
        for (int i = 0; i < 4; ++i) {
            uint4 v = regs[i];
            if constexpr (APPLY) {
                uint u[4] = {v.x, v.y, v.z, v.w};
                int kb = s * 64 + schk[i] * 8;
                #pragma unroll
                for (int j = 0; j < 4; ++j) {
                    int k = kb + 2 * j;
                    float x0 = bl(u[j]) * scl[k] + shl[k];
                    float x1 = bh(u[j]) * scl[k + 1] + shl[k + 1];
                    x0 = 1.f / (1.f + __expf(-x0));
                    x1 = 1.f / (1.f + __expf(-x1));
                    u[j] = pack2(x0, x1);
                }
                v.x = u[0]; v.y = u[1]; v.z = u[2]; v.w = u[3];
            }
            Alds[srow[i] * 8 + (schk[i] ^ (srow[i] & 7))] = v;
        }
        // reg-prefetch next K-step (overlaps barrier + MFMA)
        if (s + 1 < S) {
            #pragma unroll
            for (int i = 0; i < 4; ++i)
                regs[i] = *reinterpret_cast<const uint4*>(sga[i] + (s + 1) * 64);
        }
        __syncthreads();
        #pragma unroll
        for (int kk = 0; kk < 2; ++kk) {
            short8 a[4], b[NF];
            #pragma unroll
            for (int mf = 0; mf < 4; ++mf) {
                int R = wr * 64 + mf * 16 + rf;
                a[mf] = *reinterpret_cast<const short8*>(&Alds[R * 8 + ((kk * 4 + kg) ^ (R & 7))]);
            }
            int kglob = s * 64 + kk * 32;
            #pragma unroll
            for (int nf = 0; nf < NF; ++nf)
                b[nf] = *reinterpret_cast<const short8*>(bp[nf] + kglob);
            #pragma unroll
            for (int mf = 0; mf < 4; ++mf)
                #pragma unroll
                for (int nf = 0; nf < NF; ++nf)
                    acc[mf][nf] = __builtin_amdgcn_mfma_f32_16x16x32_bf16(a[mf], b[nf], acc[mf][nf], 0, 0, 0);
        }
        __syncthreads();
    }

    #pragma unroll
    for (int mf = 0; mf < 4; ++mf)
        #pragma unroll
        for (int nf = 0; nf < NF; ++nf) {
            int col = n0 + wc * (NF * 16) + nf * 16 + rf;
            #pragma unroll
            for (int j = 0; j < 4; ++j) {
                int row = m0 + wr * 64 + mf * 16 + kg * 4 + j;
                if (row < M) C[(size_t)row * Nout + col] = f2b(acc[mf][nf][j]);
            }
        }

    if constexpr (STATS) {
        __shared__ float bns[2][NF * 32], bnq[2][NF * 32];
        #pragma unroll
        for (int nf = 0; nf < NF; ++nf) {
            float cs = 0.f, cq = 0.f;
            #pragma unroll
            for (int mf = 0; mf < 4; ++mf)
                #pragma unroll
                for (int j = 0; j < 4; ++j) {
                    int row = m0 + wr * 64 + mf * 16 + kg * 4 + j;
                    float v = (row < M) ? acc[mf][nf][j] : 0.f;
                    cs += v; cq += v * v;
                }
            cs += __shfl_xor(cs, 16); cs += __shfl_xor(cs, 32);
            cq += __shfl_xor(cq, 16); cq += __shfl_xor(cq, 32);
            if (kg == 0) { bns[wr][wc * (NF * 16) + nf * 16 + rf] = cs; bnq[wr][wc * (NF * 16) + nf * 16 + rf] = cq; }
        }
        __syncthreads();
        if (t < NF * 32) {
            atomicAdd(&gsum[n0 + t], bns[0][t] + bns[1][t]);
            atomicAdd(&gsq[n0 + t],  bnq[0][t] + bnq[1][t]);
        }
    }
}

// ================= BN finalize =================
__global__ void k_bnfin(const float* __restrict__ sums, const float* __restrict__ sumsq,
                        const float* __restrict__ g, const float* __restrict__ beta,
                        float* __restrict__ scale, float* __restrict__ shift, int F, float invN) {
    int f = threadIdx.x;
    if (f < F) {
        float m = sums[f] * invN;
        float var = sumsq[f] * invN - m * m;
        float s = g[f] * rsqrtf(var + 1e-5f);
        scale[f] = s;
        shift[f] = beta[f] - m * s;
    }
}

// ================= decode: logits[e] = dot64( bn(h[a]), bn(h[b]) ) =================
__global__ __launch_bounds__(256) void k_decode(const ushort* __restrict__ h,
                                                const float* __restrict__ sc, const float* __restrict__ sh,
                                                const int* __restrict__ pos, const int* __restrict__ neg,
                                                int Pp, int Pn, float* __restrict__ out) {
    int gid = blockIdx.x * 16 + (threadIdx.x >> 4);
    int l = threadIdx.x & 15;
    int P = Pp + Pn;
    if (gid >= P) return;
    int a, b;
    if (gid < Pp) { a = pos[gid]; b = pos[Pp + gid]; }
    else          { int e = gid - Pp; a = neg[e]; b = neg[Pn + e]; }
    const uint2* hu = reinterpret_cast<const uint2*>(h);
    uint2 ua = hu[(size_t)a * 16 + l];
    uint2 ub = hu[(size_t)b * 16 + l];
    int f = l * 4;
    float s0 = sc[f], s1 = sc[f + 1], s2 = sc[f + 2], s3 = sc[f + 3];
    float t0 = sh[f], t1 = sh[f + 1], t2 = sh[f + 2], t3 = sh[f + 3];
    float a0 = bl(ua.x) * s0 + t0, a1 = bh(ua.x) * s1 + t1, a2 = bl(ua.y) * s2 + t2, a3 = bh(ua.y) * s3 + t3;
    float b0 = bl(ub.x) * s0 + t0, b1 = bh(ub.x) * s1 + t1, b2 = bl(ub.y) * s2 + t2, b3 = bh(ub.y) * s3 + t3;
    float d = a0 * b0 + a1 * b1 + a2 * b2 + a3 * b3;
    d += __shfl_xor(d, 1);
    d += __shfl_xor(d, 2);
    d += __shfl_xor(d, 4);
    d += __shfl_xor(d, 8);
    if (l == 0) out[gid] = d;
}

// ================= launch =================
extern "C" void kernel_launch(void* const* d_in, const int* in_sizes, int n_in,
                              void* d_out, int out_size, void* d_ws, size_t ws_size,
                              hipStream_t stream) {
    const float* x   = (const float*)d_in[0];
    const int*   ei  = (const int*)d_in[1];
    const int*   pe  = (const int*)d_in[2];
    const int*   ne  = (const int*)d_in[3];
    const float* W1  = (const float*)d_in[4];
    const float* g1  = (const float*)d_in[6];
    const float* be1 = (const float*)d_in[7];
    const float* W2  = (const float*)d_in[8];
    const float* g2  = (const float*)d_in[10];
    const float* be2 = (const float*)d_in[11];
    const float* W3  = (const float*)d_in[12];
    const float* g3  = (const float*)d_in[14];
    const float* be3 = (const float*)d_in[15];
    float* out = (float*)d_out;

    const int N  = in_sizes[0] / 128;
    const int E  = in_sizes[1] / 2;
    const int Pp = in_sizes[2] / 2;
    const int Pn = in_sizes[3] / 2;

    char* ws = (char*)d_ws;
    auto carve = [&](size_t bytes) -> char* {
        char* p = ws;
        ws += (bytes + 255) & ~(size_t)255;
        return p;
    };
    // zero zone: gh[256] + sums1[256]+sq1[256]+sums2[128]+sq2[128]+sums3[64]+sq3[64]
    char*  zz     = carve(256 * 4 + 896 * 4);
    int*   gh     = (int*)zz;
    float* sums1  = (float*)(zz + 1024);
    float* sq1    = sums1 + 256;
    float* sums2  = sq1 + 256;
    float* sq2    = sums2 + 128;
    float* sums3  = sq2 + 128;
    float* sq3    = sums3 + 64;
    size_t zz_bytes = 1024 + 896 * 4;

    int*    boff   = (int*)carve(257 * 4);
    int*    bcur   = (int*)carve(256 * 4);
    int*    rowptr = (int*)carve((size_t)(N + 1) * 4);
    float*  dinv   = (float*)carve((size_t)N * 4);
    int*    srcs   = (int*)carve((size_t)E * 4);
    int2*   pairs  = (int2*)carve((size_t)E * 8);
    float*  scale1 = (float*)carve(256 * 4);
    float*  shift1 = (float*)carve(256 * 4);
    float*  scale2 = (float*)carve(128 * 4);
    float*  shift2 = (float*)carve(128 * 4);
    float*  scale3 = (float*)carve(64 * 4);
    float*  shift3 = (float*)carve(64 * 4);
    ushort* Wt1    = (ushort*)carve(128 * 256 * 2);
    ushort* Wt2    = (ushort*)carve(256 * 128 * 2);
    ushort* Wt3    = (ushort*)carve(128 * 64 * 2);
    ushort* b1     = (ushort*)carve((size_t)N * 128 * 2);   // xb -> gemm2 out -> gemm3 out
    ushort* b2     = (ushort*)carve((size_t)N * 128 * 2);   // agg outs
    ushort* b3     = (ushort*)carve((size_t)N * 256 * 2);   // gemm1 out (h1 raw)

    const int* e_src = ei;
    const int* e_dst = ei + E;
    const int NBUCK = (N + (1 << BSHIFT) - 1) >> BSHIFT;

    hipMemsetAsync(zz, 0, zz_bytes, stream);

    // ---- CSR build: binned 2-level counting sort ----
    k_bhist<<<2048, 256, 0, stream>>>(e_dst, gh, E);
    k_bscan<<<1, 256, 0, stream>>>(gh, boff, bcur);
    k_bscatter<<<(E + SCHUNK - 1) / SCHUNK, 256, 0, stream>>>(e_src, e_dst, bcur, pairs, E);
    k_bfine<<<NBUCK, 256, 0, stream>>>(pairs, boff, rowptr, srcs, dinv, N, E);

    // ---- conversions ----
    {
        size_t n4 = (size_t)N * 128 / 4;
        k_convx<<<(int)((n4 + 255) / 256), 256, 0, stream>>>(x, b1, n4);
        k_convWT<<<(128 * 256 + 255) / 256, 256, 0, stream>>>(W1, Wt1, 128, 256);
        k_convWT<<<(256 * 128 + 255) / 256, 256, 0, stream>>>(W2, Wt2, 256, 128);
        k_convWT<<<(128 * 64 + 255) / 256, 256, 0, stream>>>(W3, Wt3, 128, 64);
    }

    const int mblk = (N + 127) / 128;
    const int agg128 = (N + 15) / 16;     // 4 nodes/wave * 4 waves
    const int agg64  = (N + 31) / 32;     // 8 nodes/wave * 4 waves

    // ---- Layer 1: agg(x) -> GEMM1 (+stats) -> bnfin1 ----
    k_agg<128><<<agg128, 256, 0, stream>>>(b1, b2, rowptr, srcs, dinv, N);
    { dim3 g(mblk, 2); k_mfma<128, 4, false, true><<<g, 256, 0, stream>>>(b2, Wt1, b3, N, 256, nullptr, nullptr, sums1, sq1); }
    k_bnfin<<<1, 256, 0, stream>>>(sums1, sq1, g1, be1, scale1, shift1, 256, 1.0f / N);

    // ---- Layer 2: GEMM2 (bn1+sig in staging) -> agg -> stats -> bnfin2 ----
    { dim3 g(mblk, 1); k_mfma<256, 4, true, false><<<g, 256, 0, stream>>>(b3, Wt2, b1, N, 128, scale1, shift1, nullptr, nullptr); }
    k_agg<128><<<agg128, 256, 0, stream>>>(b1, b2, rowptr, srcs, dinv, N);
    k_bnstats<128><<<512, 256, 0, stream>>>(b2, sums2, sq2, N);
    k_bnfin<<<1, 256, 0, stream>>>(sums2, sq2, g2, be2, scale2, shift2, 128, 1.0f / N);

    // ---- Layer 3: GEMM3 (bn2+sig in staging) -> agg -> stats -> bnfin3 ----
    { dim3 g(mblk, 1); k_mfma<128, 2, true, false><<<g, 256, 0, stream>>>(b2, Wt3, b1, N, 64, scale2, shift2, nullptr, nullptr); }
    k_agg<64><<<agg64, 256, 0, stream>>>(b1, b2, rowptr, srcs, dinv, N);
    k_bnstats<64><<<512, 256, 0, stream>>>(b2, sums3, sq3, N);
    k_bnfin<<<1, 256, 0, stream>>>(sums3, sq3, g3, be3, scale3, shift3, 64, 1.0f / N);

    // ---- decode (bn3 applied on load) ----
    k_decode<<<(Pp + Pn + 15) / 16, 256, 0, stream>>>(b2, scale3, shift3, pe, ne, Pp, Pn, out);
}